// Round 2
// baseline (684.680 us; speedup 1.0000x reference)
//
#include <hip/hip_runtime.h>
#include <hip/hip_bf16.h>

#define B_ 8
#define N_ 10000
#define E_ 160000
#define D_ 256
#define H_ 128
#define SLOPE 0.2f

// ---------------------------------------------------------------- K-detect
// One wave. Decide input formats at runtime (device-side, capture-safe):
//   flags[0]=1  -> edge_index is int64 (all sampled odd int32 words are 0)
//   flags[1]=1  -> valid_masks is 1-byte bool (some sampled int32 word > 1)
__global__ __launch_bounds__(64) void k_detect(const int* __restrict__ eidx_raw,
                                               const unsigned int* __restrict__ mask32,
                                               int* __restrict__ flags) {
    const int t = threadIdx.x;  // 0..63
    unsigned long long oddnz = __ballot(eidx_raw[2 * t + 1] != 0);
    unsigned long long mgt1  = __ballot(mask32[t] > 1u);
    if (t == 0) {
        flags[0] = (oddnz == 0ull) ? 1 : 0;
        flags[1] = (mgt1 != 0ull) ? 1 : 0;
    }
}

// ---------------------------------------------------------------- K-canon
// Canonicalize edge_index -> ce[2E] (int32), valid_masks -> cm[B*N] (uint8).
__global__ __launch_bounds__(256) void k_canon(const int* __restrict__ eidx_raw,
                                               const unsigned char* __restrict__ mask8,
                                               const unsigned int* __restrict__ mask32,
                                               const int* __restrict__ flags,
                                               int* __restrict__ ce,
                                               unsigned char* __restrict__ cm) {
    const int i = blockIdx.x * 256 + threadIdx.x;
    const int f_e = flags[0], f_m = flags[1];
    if (i < 2 * E_) ce[i] = f_e ? eidx_raw[2 * i] : eidx_raw[i];
    if (i < B_ * N_) cm[i] = f_m ? (unsigned char)(mask8[i] != 0)
                                 : (unsigned char)(mask32[i] != 0u);
}

// ---------------------------------------------------------------- K0: init
__global__ __launch_bounds__(256) void k0_init(const unsigned char* __restrict__ cm,
                                               float* __restrict__ accum,  // [2][8][256]
                                               float* __restrict__ cnt) {
    const int b = blockIdx.x;
    const int tid = threadIdx.x;
    accum[b * 256 + tid] = 0.f;          // masked sums
    accum[2048 + b * 256 + tid] = 0.f;   // full sums
    int c = 0;
    for (int i = tid; i < N_; i += 256) c += cm[b * N_ + i] ? 1 : 0;
    __shared__ int red[256];
    red[tid] = c;
    __syncthreads();
    for (int s = 128; s > 0; s >>= 1) {
        if (tid < s) red[tid] += red[tid + s];
        __syncthreads();
    }
    if (tid == 0) cnt[b] = (float)red[0];
}

// ---------------------------------------------------------------- K1: projection GEMM
// X [B*N, 256] @ W1-half [256, 128] -> node-major [(n*8+b)*128 + h]
__global__ __launch_bounds__(256) void k1_proj(const float* __restrict__ X,
                                               const float* __restrict__ W1,
                                               float* __restrict__ ps,
                                               float* __restrict__ pd) {
    const int cb = blockIdx.y;   // 0 -> ps (W1 rows 0..255), 1 -> pd (rows 256..511)
    const int rb = blockIdx.x;   // 0..624
    const int tx = threadIdx.x;  // 0..15
    const int ty = threadIdx.y;  // 0..15
    const int tid = ty * 16 + tx;

    __shared__ float As[32 * 132];  // [k][r], padded
    __shared__ float Bs[32 * 132];  // [k][c], padded

    float acc[8][8];
#pragma unroll
    for (int i = 0; i < 8; i++)
#pragma unroll
        for (int j = 0; j < 8; j++) acc[i][j] = 0.f;

    const int row_base = rb * 128;
    float* __restrict__ outp = cb ? pd : ps;

    for (int kc = 0; kc < 8; ++kc) {
#pragma unroll
        for (int i = 0; i < 4; i++) {
            int f = i * 256 + tid;
            int r = f >> 3;
            int kf = f & 7;
            float4 v = *(const float4*)&X[(size_t)(row_base + r) * 256 + kc * 32 + kf * 4];
            As[(kf * 4 + 0) * 132 + r] = v.x;
            As[(kf * 4 + 1) * 132 + r] = v.y;
            As[(kf * 4 + 2) * 132 + r] = v.z;
            As[(kf * 4 + 3) * 132 + r] = v.w;
        }
#pragma unroll
        for (int i = 0; i < 4; i++) {
            int f = i * 256 + tid;
            int k = f >> 5;
            int cf = f & 31;
            float4 v = *(const float4*)&W1[(size_t)(cb * 256 + kc * 32 + k) * 128 + cf * 4];
            *(float4*)&Bs[k * 132 + cf * 4] = v;
        }
        __syncthreads();

#pragma unroll 4
        for (int kk = 0; kk < 32; ++kk) {
            float4 a0 = *(float4*)&As[kk * 132 + ty * 8];
            float4 a1 = *(float4*)&As[kk * 132 + ty * 8 + 4];
            float4 b0 = *(float4*)&Bs[kk * 132 + tx * 8];
            float4 b1 = *(float4*)&Bs[kk * 132 + tx * 8 + 4];
            float a_[8] = {a0.x, a0.y, a0.z, a0.w, a1.x, a1.y, a1.z, a1.w};
            float b_[8] = {b0.x, b0.y, b0.z, b0.w, b1.x, b1.y, b1.z, b1.w};
#pragma unroll
            for (int i = 0; i < 8; i++)
#pragma unroll
                for (int j = 0; j < 8; j++) acc[i][j] = fmaf(a_[i], b_[j], acc[i][j]);
        }
        __syncthreads();
    }

#pragma unroll
    for (int i = 0; i < 8; i++) {
        int r = row_base + ty * 8 + i;
        int b = r / N_;
        int n = r - b * N_;
        float* p = outp + ((size_t)(n * 8 + b)) * 128 + tx * 8;
        *(float4*)p = make_float4(acc[i][0], acc[i][1], acc[i][2], acc[i][3]);
        *(float4*)(p + 4) = make_float4(acc[i][4], acc[i][5], acc[i][6], acc[i][7]);
    }
}

// ---------------------------------------------------------------- K2: edge scores
__global__ __launch_bounds__(256) void k2_scores(const float* __restrict__ ps,
                                                 const float* __restrict__ pd,
                                                 const int* __restrict__ ce,
                                                 const float* __restrict__ b1,
                                                 const float* __restrict__ W2,
                                                 const float* __restrict__ b2,
                                                 const float* __restrict__ eattr,
                                                 float* __restrict__ scores) {
    __shared__ float sb1[128];
    __shared__ float sw2[128];
    const int tid = threadIdx.x;
    if (tid < 128) sb1[tid] = b1[tid];
    else sw2[tid - 128] = W2[tid - 128];
    __syncthreads();

    const int wave = tid >> 6;
    const int lane = tid & 63;
    const int e = blockIdx.x * 4 + wave;

    const int src = ce[e];
    const int dst = ce[E_ + e];
    const int b = lane >> 3;
    const int hi = (lane & 7) * 16;

    const float4* pps = (const float4*)&ps[((size_t)src * 8 + b) * 128 + hi];
    const float4* ppd = (const float4*)&pd[((size_t)dst * 8 + b) * 128 + hi];

    float partial = 0.f;
#pragma unroll
    for (int q = 0; q < 4; q++) {
        float4 s4 = pps[q];
        float4 d4 = ppd[q];
        float h;
        h = s4.x + d4.x + sb1[hi + q * 4 + 0]; h = h >= 0.f ? h : SLOPE * h; partial = fmaf(h, sw2[hi + q * 4 + 0], partial);
        h = s4.y + d4.y + sb1[hi + q * 4 + 1]; h = h >= 0.f ? h : SLOPE * h; partial = fmaf(h, sw2[hi + q * 4 + 1], partial);
        h = s4.z + d4.z + sb1[hi + q * 4 + 2]; h = h >= 0.f ? h : SLOPE * h; partial = fmaf(h, sw2[hi + q * 4 + 2], partial);
        h = s4.w + d4.w + sb1[hi + q * 4 + 3]; h = h >= 0.f ? h : SLOPE * h; partial = fmaf(h, sw2[hi + q * 4 + 3], partial);
    }
    partial += __shfl_xor(partial, 1);
    partial += __shfl_xor(partial, 2);
    partial += __shfl_xor(partial, 4);

    if ((lane & 7) == 0) {
        float s = (partial + b2[0]) * eattr[e];
        scores[(size_t)b * E_ + e] = s;
    }
}

// ---------------------------------------------------------------- K3: softmax in place
__global__ __launch_bounds__(1024) void k3_softmax(float* __restrict__ sc) {
    const int b = blockIdx.x;
    const int tid = threadIdx.x;
    float* x = sc + (size_t)b * E_;

    __shared__ float redf[1024];
    __shared__ double redd[1024];

    float m = -3.4e38f;
    for (int i = tid; i < E_; i += 1024) m = fmaxf(m, x[i]);
    redf[tid] = m;
    __syncthreads();
    for (int s = 512; s > 0; s >>= 1) {
        if (tid < s) redf[tid] = fmaxf(redf[tid], redf[tid + s]);
        __syncthreads();
    }
    m = redf[0];

    float psum = 0.f;
    for (int i = tid; i < E_; i += 1024) psum += expf(x[i] - m);
    redd[tid] = (double)psum;
    __syncthreads();
    for (int s = 512; s > 0; s >>= 1) {
        if (tid < s) redd[tid] += redd[tid + s];
        __syncthreads();
    }
    const float inv = (float)(1.0 / redd[0]);

    for (int i = tid; i < E_; i += 1024) x[i] = expf(x[i] - m) * inv;
}

// ---------------------------------------------------------------- K4: weighted accumulation
#define EPB 157
__global__ __launch_bounds__(256) void k4_accum(const float* __restrict__ X,
                                                const float* __restrict__ w,
                                                const int* __restrict__ ce,
                                                const unsigned char* __restrict__ cm,
                                                float* __restrict__ accum) {
    const int tid = threadIdx.x;  // d
    const int e0 = blockIdx.x * EPB;
    const int e1 = min(E_, e0 + EPB);

    float am[8], af[8];
#pragma unroll
    for (int b = 0; b < 8; b++) { am[b] = 0.f; af[b] = 0.f; }

    for (int e = e0; e < e1; ++e) {
        const int src = ce[e];
        const int dst = ce[E_ + e];
#pragma unroll
        for (int b = 0; b < 8; b++) {
            float wv = w[(size_t)b * E_ + e];
            float val = X[((size_t)b * N_ + dst) * 256 + tid];
            af[b] = fmaf(wv, val, af[b]);
            float wm = cm[b * N_ + src] ? wv : 0.f;
            am[b] = fmaf(wm, val, am[b]);
        }
    }
#pragma unroll
    for (int b = 0; b < 8; b++) {
        atomicAdd(&accum[b * 256 + tid], am[b]);
        atomicAdd(&accum[2048 + b * 256 + tid], af[b]);
    }
}

// ---------------------------------------------------------------- K5: finalize
__global__ __launch_bounds__(256) void k5_final(const float* __restrict__ accum,
                                                const float* __restrict__ cnt,
                                                float* __restrict__ gf) {
    const int b = blockIdx.x;
    const int d = threadIdx.x;
    const float c = cnt[b];
    float v;
    if (c > 0.f) v = accum[b * 256 + d] / c;
    else v = accum[2048 + b * 256 + d] / (float)N_;
    gf[b * 256 + d] = v;
}

// ---------------------------------------------------------------- launch
extern "C" void kernel_launch(void* const* d_in, const int* in_sizes, int n_in,
                              void* d_out, int out_size, void* d_ws, size_t ws_size,
                              hipStream_t stream) {
    const float* X     = (const float*)d_in[0];          // [B,N,D]
    const float* eattr = (const float*)d_in[1];          // [E,1]
    const float* W1    = (const float*)d_in[2];          // [2D,H]
    const float* b1    = (const float*)d_in[3];          // [H]
    const float* W2    = (const float*)d_in[4];          // [H,1]
    const float* b2    = (const float*)d_in[5];          // [1]
    const int*   eidx_raw = (const int*)d_in[6];         // [2,E] int32 or int64
    const unsigned char* mask8 = (const unsigned char*)d_in[7];
    const unsigned int*  mask32 = (const unsigned int*)d_in[7];

    float* out  = (float*)d_out;
    float* gf   = out;          // [B,D]
    float* wout = out + 2048;   // [B,E] scores, softmaxed in place

    float* ps    = (float*)d_ws;                       // [N,B,H]
    float* pd    = ps + (size_t)N_ * 8 * 128;          // [N,B,H]
    float* accum = pd + (size_t)N_ * 8 * 128;          // [2][8][256]
    float* cnt   = accum + 4096;                       // [8]
    int*   flags = (int*)(cnt + 8);                    // [2]
    int*   ce    = flags + 2;                          // [2E]
    unsigned char* cm = (unsigned char*)(ce + 2 * E_); // [B*N]

    hipLaunchKernelGGL(k_detect, dim3(1), dim3(64), 0, stream, eidx_raw, mask32, flags);
    hipLaunchKernelGGL(k_canon, dim3((2 * E_ + 255) / 256), dim3(256), 0, stream,
                       eidx_raw, mask8, mask32, flags, ce, cm);
    hipLaunchKernelGGL(k0_init, dim3(8), dim3(256), 0, stream, cm, accum, cnt);
    hipLaunchKernelGGL(k1_proj, dim3(625, 2), dim3(16, 16), 0, stream, X, W1, ps, pd);
    hipLaunchKernelGGL(k2_scores, dim3(E_ / 4), dim3(256), 0, stream,
                       ps, pd, ce, b1, W2, b2, eattr, wout);
    hipLaunchKernelGGL(k3_softmax, dim3(8), dim3(1024), 0, stream, wout);
    hipLaunchKernelGGL(k4_accum, dim3((E_ + EPB - 1) / EPB), dim3(256), 0, stream,
                       X, wout, ce, cm, accum);
    hipLaunchKernelGGL(k5_final, dim3(8), dim3(256), 0, stream, accum, cnt, gf);
}

// Round 3
// 485.497 us; speedup vs baseline: 1.4103x; 1.4103x over previous
//
#include <hip/hip_runtime.h>
#include <hip/hip_bf16.h>
#include <hip/hip_fp16.h>

#define B_ 8
#define N_ 10000
#define E_ 160000
#define D_ 256
#define H_ 128
#define SLOPE 0.2f
#define NCHUNK 50   // node chunks for dense weighted sum (200 nodes/chunk)

// ---------------------------------------------------------------- K-detect
__global__ __launch_bounds__(64) void k_detect(const int* __restrict__ eidx_raw,
                                               const unsigned int* __restrict__ mask32,
                                               int* __restrict__ flags) {
    const int t = threadIdx.x;
    unsigned long long oddnz = __ballot(eidx_raw[2 * t + 1] != 0);
    unsigned long long mgt1  = __ballot(mask32[t] > 1u);
    if (t == 0) {
        flags[0] = (oddnz == 0ull) ? 1 : 0;  // edge_index is int64
        flags[1] = (mgt1 != 0ull) ? 1 : 0;   // mask is 1-byte bool
    }
}

// ---------------------------------------------------------------- K-canon
// canonicalize edge_index->int32, mask->uint8; zero Wm/Wf (160000 floats)
__global__ __launch_bounds__(256) void k_canon(const int* __restrict__ eidx_raw,
                                               const unsigned char* __restrict__ mask8,
                                               const unsigned int* __restrict__ mask32,
                                               const int* __restrict__ flags,
                                               int* __restrict__ ce,
                                               unsigned char* __restrict__ cm,
                                               float* __restrict__ wz) {
    const int i = blockIdx.x * 256 + threadIdx.x;
    const int f_e = flags[0], f_m = flags[1];
    if (i < 2 * E_) ce[i] = f_e ? eidx_raw[2 * i] : eidx_raw[i];
    if (i < B_ * N_) cm[i] = f_m ? (unsigned char)(mask8[i] != 0)
                                 : (unsigned char)(mask32[i] != 0u);
    if (i < 2 * B_ * N_) wz[i] = 0.f;  // Wm then Wf, contiguous
}

// ---------------------------------------------------------------- K0: count valid nodes
__global__ __launch_bounds__(256) void k0_init(const unsigned char* __restrict__ cm,
                                               float* __restrict__ cnt) {
    const int b = blockIdx.x;
    const int tid = threadIdx.x;
    int c = 0;
    for (int i = tid; i < N_; i += 256) c += cm[b * N_ + i] ? 1 : 0;
    __shared__ int red[256];
    red[tid] = c;
    __syncthreads();
    for (int s = 128; s > 0; s >>= 1) {
        if (tid < s) red[tid] += red[tid + s];
        __syncthreads();
    }
    if (tid == 0) cnt[b] = (float)red[0];
}

// ---------------------------------------------------------------- K1: projection GEMM (fp32 -> fp16 out)
// X [B*N,256] @ W1-half [256,128] -> node-major fp16 [(n*8+b)*128 + h]
__global__ __launch_bounds__(256) void k1_proj(const float* __restrict__ X,
                                               const float* __restrict__ W1,
                                               __half* __restrict__ ps,
                                               __half* __restrict__ pd) {
    const int cb = blockIdx.y;
    const int rb = blockIdx.x;
    const int tx = threadIdx.x;
    const int ty = threadIdx.y;
    const int tid = ty * 16 + tx;

    __shared__ float As[32 * 132];
    __shared__ float Bs[32 * 132];

    float acc[8][8];
#pragma unroll
    for (int i = 0; i < 8; i++)
#pragma unroll
        for (int j = 0; j < 8; j++) acc[i][j] = 0.f;

    const int row_base = rb * 128;
    __half* __restrict__ outp = cb ? pd : ps;

    for (int kc = 0; kc < 8; ++kc) {
#pragma unroll
        for (int i = 0; i < 4; i++) {
            int f = i * 256 + tid;
            int r = f >> 3;
            int kf = f & 7;
            float4 v = *(const float4*)&X[(size_t)(row_base + r) * 256 + kc * 32 + kf * 4];
            As[(kf * 4 + 0) * 132 + r] = v.x;
            As[(kf * 4 + 1) * 132 + r] = v.y;
            As[(kf * 4 + 2) * 132 + r] = v.z;
            As[(kf * 4 + 3) * 132 + r] = v.w;
        }
#pragma unroll
        for (int i = 0; i < 4; i++) {
            int f = i * 256 + tid;
            int k = f >> 5;
            int cf = f & 31;
            float4 v = *(const float4*)&W1[(size_t)(cb * 256 + kc * 32 + k) * 128 + cf * 4];
            *(float4*)&Bs[k * 132 + cf * 4] = v;
        }
        __syncthreads();

#pragma unroll 4
        for (int kk = 0; kk < 32; ++kk) {
            float4 a0 = *(float4*)&As[kk * 132 + ty * 8];
            float4 a1 = *(float4*)&As[kk * 132 + ty * 8 + 4];
            float4 b0 = *(float4*)&Bs[kk * 132 + tx * 8];
            float4 b1 = *(float4*)&Bs[kk * 132 + tx * 8 + 4];
            float a_[8] = {a0.x, a0.y, a0.z, a0.w, a1.x, a1.y, a1.z, a1.w};
            float b_[8] = {b0.x, b0.y, b0.z, b0.w, b1.x, b1.y, b1.z, b1.w};
#pragma unroll
            for (int i = 0; i < 8; i++)
#pragma unroll
                for (int j = 0; j < 8; j++) acc[i][j] = fmaf(a_[i], b_[j], acc[i][j]);
        }
        __syncthreads();
    }

#pragma unroll
    for (int i = 0; i < 8; i++) {
        int r = row_base + ty * 8 + i;
        int b = r / N_;
        int n = r - b * N_;
        union { __half2 h2[4]; float4 f4; } pk;
        pk.h2[0] = __floats2half2_rn(acc[i][0], acc[i][1]);
        pk.h2[1] = __floats2half2_rn(acc[i][2], acc[i][3]);
        pk.h2[2] = __floats2half2_rn(acc[i][4], acc[i][5]);
        pk.h2[3] = __floats2half2_rn(acc[i][6], acc[i][7]);
        *(float4*)&outp[((size_t)(n * 8 + b)) * 128 + tx * 8] = pk.f4;
    }
}

// ---------------------------------------------------------------- K2: edge scores (fp16 gathers)
__global__ __launch_bounds__(256) void k2_scores(const __half* __restrict__ ps,
                                                 const __half* __restrict__ pd,
                                                 const int* __restrict__ ce,
                                                 const float* __restrict__ b1,
                                                 const float* __restrict__ W2,
                                                 const float* __restrict__ b2,
                                                 const float* __restrict__ eattr,
                                                 float* __restrict__ scores) {
    __shared__ float sb1[128];
    __shared__ float sw2[128];
    const int tid = threadIdx.x;
    if (tid < 128) sb1[tid] = b1[tid];
    else sw2[tid - 128] = W2[tid - 128];
    __syncthreads();

    const int wave = tid >> 6;
    const int lane = tid & 63;
    const int e = blockIdx.x * 4 + wave;

    const int src = ce[e];
    const int dst = ce[E_ + e];
    const int b = lane >> 3;
    const int hi = (lane & 7) * 16;

    const float4* pps = (const float4*)&ps[((size_t)src * 8 + b) * 128 + hi];
    const float4* ppd = (const float4*)&pd[((size_t)dst * 8 + b) * 128 + hi];

    float partial = 0.f;
#pragma unroll
    for (int q = 0; q < 2; q++) {
        float4 rs = pps[q];
        float4 rd = ppd[q];
        const __half2* hs = (const __half2*)&rs;
        const __half2* hd = (const __half2*)&rd;
#pragma unroll
        for (int j = 0; j < 4; j++) {
            float2 fs = __half22float2(hs[j]);
            float2 fd = __half22float2(hd[j]);
            int idx = hi + q * 8 + j * 2;
            float h0 = fs.x + fd.x + sb1[idx];     h0 = h0 >= 0.f ? h0 : SLOPE * h0;
            float h1 = fs.y + fd.y + sb1[idx + 1]; h1 = h1 >= 0.f ? h1 : SLOPE * h1;
            partial = fmaf(h0, sw2[idx], partial);
            partial = fmaf(h1, sw2[idx + 1], partial);
        }
    }
    partial += __shfl_xor(partial, 1);
    partial += __shfl_xor(partial, 2);
    partial += __shfl_xor(partial, 4);

    if ((lane & 7) == 0) {
        scores[(size_t)b * E_ + e] = (partial + b2[0]) * eattr[e];
    }
}

// ---------------------------------------------------------------- K3a: partial max (grid 32 x 8)
__global__ __launch_bounds__(256) void k3a_max(const float* __restrict__ sc,
                                               float* __restrict__ pmax) {
    const int b = blockIdx.y, c = blockIdx.x, tid = threadIdx.x;
    const float* x = sc + (size_t)b * E_;
    const int i0 = c * (E_ / 32);
    float mv = -3.4e38f;
    for (int i = i0 + tid; i < i0 + E_ / 32; i += 256) mv = fmaxf(mv, x[i]);
    __shared__ float red[256];
    red[tid] = mv;
    __syncthreads();
    for (int s = 128; s > 0; s >>= 1) {
        if (tid < s) red[tid] = fmaxf(red[tid], red[tid + s]);
        __syncthreads();
    }
    if (tid == 0) pmax[b * 32 + c] = red[0];
}

// ---------------------------------------------------------------- K3b: final max (1 block)
__global__ __launch_bounds__(256) void k3b_maxred(const float* __restrict__ pmax,
                                                  float* __restrict__ m) {
    const int t = threadIdx.x;
    float v = pmax[t];
#pragma unroll
    for (int k = 1; k <= 16; k <<= 1) v = fmaxf(v, __shfl_xor(v, k));
    if ((t & 31) == 0) m[t >> 5] = v;
}

// ---------------------------------------------------------------- K3c: partial exp-sums (grid 32 x 8)
__global__ __launch_bounds__(256) void k3c_sum(const float* __restrict__ sc,
                                               const float* __restrict__ m,
                                               double* __restrict__ psum) {
    const int b = blockIdx.y, c = blockIdx.x, tid = threadIdx.x;
    const float* x = sc + (size_t)b * E_;
    const float mv = m[b];
    const int i0 = c * (E_ / 32);
    double s = 0.0;
    for (int i = i0 + tid; i < i0 + E_ / 32; i += 256) s += (double)expf(x[i] - mv);
    __shared__ double red[256];
    red[tid] = s;
    __syncthreads();
    for (int st = 128; st > 0; st >>= 1) {
        if (tid < st) red[tid] += red[tid + st];
        __syncthreads();
    }
    if (tid == 0) psum[b * 32 + c] = red[0];
}

// ---------------------------------------------------------------- K3d: final sum -> inv (1 block)
__global__ __launch_bounds__(256) void k3d_sumred(const double* __restrict__ psum,
                                                  float* __restrict__ inv) {
    const int t = threadIdx.x;
    double v = psum[t];
#pragma unroll
    for (int k = 1; k <= 16; k <<= 1) v += __shfl_xor(v, k);
    if ((t & 31) == 0) inv[t >> 5] = (float)(1.0 / v);
}

// ---------------------------------------------------------------- K3e: normalize + scatter node weights
// w[b,e] = exp(s-m)*inv  (written to output);  Wf[b,dst] += w;  Wm[b,dst] += mask[b,src]*w
__global__ __launch_bounds__(256) void k3e_norm_scatter(float* __restrict__ sc,
                                                        const int* __restrict__ ce,
                                                        const unsigned char* __restrict__ cm,
                                                        const float* __restrict__ m,
                                                        const float* __restrict__ inv,
                                                        float* __restrict__ Wm,
                                                        float* __restrict__ Wf) {
    const int e = blockIdx.x * 256 + threadIdx.x;
    const int src = ce[e];
    const int dst = ce[E_ + e];
#pragma unroll
    for (int b = 0; b < 8; b++) {
        float wv = expf(sc[(size_t)b * E_ + e] - m[b]) * inv[b];
        sc[(size_t)b * E_ + e] = wv;  // in-place: scores buffer IS the w output
        atomicAdd(&Wf[b * N_ + dst], wv);
        if (cm[b * N_ + src]) atomicAdd(&Wm[b * N_ + dst], wv);
    }
}

// ---------------------------------------------------------------- K4b: dense weighted sum over X
// gpart[c][0][b][d] = sum over chunk nodes of Wm*X ; [c][1][b][d] with Wf
__global__ __launch_bounds__(256) void k4b_wsum(const float* __restrict__ X,
                                                const float* __restrict__ Wm,
                                                const float* __restrict__ Wf,
                                                float* __restrict__ gpart) {
    const int c = blockIdx.x;  // 0..NCHUNK-1
    const int b = blockIdx.y;  // 0..7
    const int tx = threadIdx.x & 63;   // float4 column
    const int ty = threadIdx.x >> 6;   // 0..3
    const int npc = N_ / NCHUNK;       // 200
    const int n0 = c * npc;

    const float4* X4 = (const float4*)(X + (size_t)b * N_ * 256);
    float4 am = {0.f, 0.f, 0.f, 0.f};
    float4 af = {0.f, 0.f, 0.f, 0.f};

    for (int n = n0 + ty; n < n0 + npc; n += 4) {
        float wm = Wm[b * N_ + n];
        float wf = Wf[b * N_ + n];
        float4 v = X4[(size_t)n * 64 + tx];
        am.x = fmaf(wm, v.x, am.x); am.y = fmaf(wm, v.y, am.y);
        am.z = fmaf(wm, v.z, am.z); am.w = fmaf(wm, v.w, am.w);
        af.x = fmaf(wf, v.x, af.x); af.y = fmaf(wf, v.y, af.y);
        af.z = fmaf(wf, v.z, af.z); af.w = fmaf(wf, v.w, af.w);
    }

    __shared__ float4 red[256];
    red[threadIdx.x] = am;
    __syncthreads();
    if (ty == 0) {
        float4 r1 = red[tx + 64], r2 = red[tx + 128], r3 = red[tx + 192];
        am.x += r1.x + r2.x + r3.x; am.y += r1.y + r2.y + r3.y;
        am.z += r1.z + r2.z + r3.z; am.w += r1.w + r2.w + r3.w;
    }
    __syncthreads();
    red[threadIdx.x] = af;
    __syncthreads();
    if (ty == 0) {
        float4 r1 = red[tx + 64], r2 = red[tx + 128], r3 = red[tx + 192];
        af.x += r1.x + r2.x + r3.x; af.y += r1.y + r2.y + r3.y;
        af.z += r1.z + r2.z + r3.z; af.w += r1.w + r2.w + r3.w;
        float4* gp4 = (float4*)gpart;
        gp4[((c * 2 + 0) * 8 + b) * 64 + tx] = am;
        gp4[((c * 2 + 1) * 8 + b) * 64 + tx] = af;
    }
}

// ---------------------------------------------------------------- K5: finalize
__global__ __launch_bounds__(256) void k5_final(const float* __restrict__ gpart,
                                                const float* __restrict__ cnt,
                                                float* __restrict__ gf) {
    const int b = blockIdx.x;
    const int d = threadIdx.x;
    float sm = 0.f, sf = 0.f;
    for (int c = 0; c < NCHUNK; c++) {
        sm += gpart[((c * 2 + 0) * 8 + b) * 256 + d];
        sf += gpart[((c * 2 + 1) * 8 + b) * 256 + d];
    }
    const float cn = cnt[b];
    gf[b * 256 + d] = (cn > 0.f) ? (sm / cn) : (sf / (float)N_);
}

// ---------------------------------------------------------------- launch
extern "C" void kernel_launch(void* const* d_in, const int* in_sizes, int n_in,
                              void* d_out, int out_size, void* d_ws, size_t ws_size,
                              hipStream_t stream) {
    const float* X     = (const float*)d_in[0];
    const float* eattr = (const float*)d_in[1];
    const float* W1    = (const float*)d_in[2];
    const float* b1    = (const float*)d_in[3];
    const float* W2    = (const float*)d_in[4];
    const float* b2    = (const float*)d_in[5];
    const int*   eidx_raw = (const int*)d_in[6];
    const unsigned char* mask8 = (const unsigned char*)d_in[7];
    const unsigned int*  mask32 = (const unsigned int*)d_in[7];

    float* out  = (float*)d_out;
    float* gf   = out;          // [B,D]
    float* wout = out + 2048;   // [B,E]: scores -> softmaxed w in place

    __half* ps_h = (__half*)d_ws;                         // [N*8*128] fp16
    __half* pd_h = ps_h + (size_t)N_ * 8 * 128;
    int* ce = (int*)(pd_h + (size_t)N_ * 8 * 128);        // [2E]
    unsigned char* cm = (unsigned char*)(ce + 2 * E_);    // [B*N]
    float* Wm  = (float*)(cm + B_ * N_);                  // [B*N]
    float* Wf  = Wm + B_ * N_;                            // [B*N]
    float* cnt = Wf + B_ * N_;                            // [8]
    int* flags = (int*)(cnt + 8);                         // [2]
    float* pmax = (float*)(flags + 2);                    // [256]
    float* mbuf = pmax + 256;                             // [8]
    float* invb = mbuf + 8;                               // [8]
    double* psum = (double*)(((uintptr_t)(invb + 8) + 15) & ~(uintptr_t)15);  // [256]
    float* gpart = (float*)(psum + 256);                  // [NCHUNK*2*8*256]

    hipLaunchKernelGGL(k_detect, dim3(1), dim3(64), 0, stream, eidx_raw, mask32, flags);
    hipLaunchKernelGGL(k_canon, dim3(1250), dim3(256), 0, stream,
                       eidx_raw, mask8, mask32, flags, ce, cm, Wm);
    hipLaunchKernelGGL(k0_init, dim3(8), dim3(256), 0, stream, cm, cnt);
    hipLaunchKernelGGL(k1_proj, dim3(625, 2), dim3(16, 16), 0, stream, X, W1, ps_h, pd_h);
    hipLaunchKernelGGL(k2_scores, dim3(E_ / 4), dim3(256), 0, stream,
                       ps_h, pd_h, ce, b1, W2, b2, eattr, wout);
    hipLaunchKernelGGL(k3a_max, dim3(32, 8), dim3(256), 0, stream, wout, pmax);
    hipLaunchKernelGGL(k3b_maxred, dim3(1), dim3(256), 0, stream, pmax, mbuf);
    hipLaunchKernelGGL(k3c_sum, dim3(32, 8), dim3(256), 0, stream, wout, mbuf, psum);
    hipLaunchKernelGGL(k3d_sumred, dim3(1), dim3(256), 0, stream, psum, invb);
    hipLaunchKernelGGL(k3e_norm_scatter, dim3(E_ / 256), dim3(256), 0, stream,
                       wout, ce, cm, mbuf, invb, Wm, Wf);
    hipLaunchKernelGGL(k4b_wsum, dim3(NCHUNK, 8), dim3(256), 0, stream, X, Wm, Wf, gpart);
    hipLaunchKernelGGL(k5_final, dim3(8), dim3(256), 0, stream, gpart, cnt, gf);
}

// Round 4
// 398.047 us; speedup vs baseline: 1.7201x; 1.2197x over previous
//
#include <hip/hip_runtime.h>
#include <hip/hip_bf16.h>
#include <hip/hip_fp16.h>

#define B_ 8
#define N_ 10000
#define E_ 160000
#define D_ 256
#define H_ 128
#define SLOPE 0.2f
#define NCHUNK 50   // node chunks for dense weighted sum (200 nodes/chunk)

typedef __attribute__((ext_vector_type(8))) _Float16 v8h;
typedef __attribute__((ext_vector_type(4))) _Float16 v4h;
typedef __attribute__((ext_vector_type(4))) float f32x4;

// ---------------------------------------------------------------- K-detect
__global__ __launch_bounds__(64) void k_detect(const int* __restrict__ eidx_raw,
                                               const unsigned int* __restrict__ mask32,
                                               int* __restrict__ flags) {
    const int t = threadIdx.x;
    unsigned long long oddnz = __ballot(eidx_raw[2 * t + 1] != 0);
    unsigned long long mgt1  = __ballot(mask32[t] > 1u);
    if (t == 0) {
        flags[0] = (oddnz == 0ull) ? 1 : 0;  // edge_index is int64
        flags[1] = (mgt1 != 0ull) ? 1 : 0;   // mask is 1-byte bool
    }
}

// ---------------------------------------------------------------- K-canon
__global__ __launch_bounds__(256) void k_canon(const int* __restrict__ eidx_raw,
                                               const unsigned char* __restrict__ mask8,
                                               const unsigned int* __restrict__ mask32,
                                               const int* __restrict__ flags,
                                               int* __restrict__ ce,
                                               unsigned char* __restrict__ cm,
                                               float* __restrict__ wz) {
    const int i = blockIdx.x * 256 + threadIdx.x;
    const int f_e = flags[0], f_m = flags[1];
    if (i < 2 * E_) ce[i] = f_e ? eidx_raw[2 * i] : eidx_raw[i];
    if (i < B_ * N_) cm[i] = f_m ? (unsigned char)(mask8[i] != 0)
                                 : (unsigned char)(mask32[i] != 0u);
    if (i < 2 * B_ * N_) wz[i] = 0.f;  // Wm then Wf, contiguous
}

// ---------------------------------------------------------------- kW: W1 -> fp16 transposed
// Wt[c][f][k] = W1[c*256+k][f] ; c in {0,1}, f<128, k<256
__global__ __launch_bounds__(256) void kW(const float* __restrict__ W1,
                                          __half* __restrict__ Wt) {
    const int i = blockIdx.x * 256 + threadIdx.x;  // 0..65535
    const int f = i & 127;
    const int row = i >> 7;       // 0..511
    const int c = row >> 8, k = row & 255;
    Wt[((c * 128 + f) * 256) + k] = __float2half(W1[row * 128 + f]);
}

// ---------------------------------------------------------------- K0: count valid nodes
__global__ __launch_bounds__(256) void k0_init(const unsigned char* __restrict__ cm,
                                               float* __restrict__ cnt) {
    const int b = blockIdx.x;
    const int tid = threadIdx.x;
    int c = 0;
    for (int i = tid; i < N_; i += 256) c += cm[b * N_ + i] ? 1 : 0;
    __shared__ int red[256];
    red[tid] = c;
    __syncthreads();
    for (int s = 128; s > 0; s >>= 1) {
        if (tid < s) red[tid] += red[tid + s];
        __syncthreads();
    }
    if (tid == 0) cnt[b] = (float)red[0];
}

// ---------------------------------------------------------------- K1: MFMA projection GEMM
// C[row=b*N+n][feat] = X[row] . Wt[cb][feat]  (fp16 in, fp32 acc, fp16 out)
// out layout node-major: outp[(n*8+b)*128 + feat]
__global__ __launch_bounds__(256) void k1_mfma(const float* __restrict__ X,
                                               const __half* __restrict__ Wt,
                                               __half* __restrict__ ps,
                                               __half* __restrict__ pd) {
    const int cb = blockIdx.y;   // 0 -> ps, 1 -> pd
    const int rb = blockIdx.x;   // 0..624
    const int tid = threadIdx.x;
    const int wave = tid >> 6, lane = tid & 63;
    const int quad = lane >> 4, l16 = lane & 15;

    __shared__ _Float16 Xs[128 * 40];  // [node][k], pad 40
    __shared__ _Float16 Ws[128 * 40];  // [feat][k], pad 40

    f32x4 acc[2][8];
#pragma unroll
    for (int i = 0; i < 2; i++)
#pragma unroll
        for (int j = 0; j < 8; j++) acc[i][j] = (f32x4){0.f, 0.f, 0.f, 0.f};

    const int row_base = rb * 128;
    const __half* __restrict__ Wh = Wt + (size_t)cb * 128 * 256;
    __half* __restrict__ outp = cb ? pd : ps;

    const int sr = tid >> 1;       // staging row 0..127
    const int sh = tid & 1;        // k-half (16 elems)

    for (int kc = 0; kc < 8; ++kc) {
        // stage X tile: 128 rows x 32 k, fp32 -> fp16
        {
            const float4* src = (const float4*)&X[(size_t)(row_base + sr) * 256 + kc * 32 + sh * 16];
            _Float16* dst = &Xs[sr * 40 + sh * 16];
#pragma unroll
            for (int j = 0; j < 4; ++j) {
                float4 v = src[j];
                v4h p = {(_Float16)v.x, (_Float16)v.y, (_Float16)v.z, (_Float16)v.w};
                *(v4h*)&dst[j * 4] = p;
            }
        }
        // stage W tile: 128 feats x 32 k (already fp16)
        {
            const float4* src = (const float4*)&Wh[(size_t)sr * 256 + kc * 32 + sh * 16];
            float4 v0 = src[0], v1 = src[1];
            *(float4*)&Ws[sr * 40 + sh * 16] = v0;
            *(float4*)&Ws[sr * 40 + sh * 16 + 8] = v1;
        }
        __syncthreads();

        v8h wf[2];
#pragma unroll
        for (int ft = 0; ft < 2; ++ft)
            wf[ft] = *(v8h*)&Ws[(wave * 32 + ft * 16 + l16) * 40 + quad * 8];
#pragma unroll
        for (int nt = 0; nt < 8; ++nt) {
            v8h xf = *(v8h*)&Xs[(nt * 16 + l16) * 40 + quad * 8];
            acc[0][nt] = __builtin_amdgcn_mfma_f32_16x16x32_f16(wf[0], xf, acc[0][nt], 0, 0, 0);
            acc[1][nt] = __builtin_amdgcn_mfma_f32_16x16x32_f16(wf[1], xf, acc[1][nt], 0, 0, 0);
        }
        __syncthreads();
    }

    // epilogue: lane holds feats quad*4+0..3 (consecutive) of node nt*16+l16
#pragma unroll
    for (int nt = 0; nt < 8; ++nt) {
        const int R = row_base + nt * 16 + l16;
        const int b = R / N_;
        const int n = R - b * N_;
        __half* base = outp + ((size_t)(n * 8 + b)) * 128 + wave * 32 + quad * 4;
#pragma unroll
        for (int ft = 0; ft < 2; ++ft) {
            f32x4 a = acc[ft][nt];
            v4h h = {(_Float16)a.x, (_Float16)a.y, (_Float16)a.z, (_Float16)a.w};
            *(v4h*)(base + ft * 16) = h;
        }
    }
}

// ---------------------------------------------------------------- K2: edge scores (fp16 gathers)
__global__ __launch_bounds__(256) void k2_scores(const __half* __restrict__ ps,
                                                 const __half* __restrict__ pd,
                                                 const int* __restrict__ ce,
                                                 const float* __restrict__ b1,
                                                 const float* __restrict__ W2,
                                                 const float* __restrict__ b2,
                                                 const float* __restrict__ eattr,
                                                 float* __restrict__ scores) {
    __shared__ float sb1[128];
    __shared__ float sw2[128];
    const int tid = threadIdx.x;
    if (tid < 128) sb1[tid] = b1[tid];
    else sw2[tid - 128] = W2[tid - 128];
    __syncthreads();

    const int wave = tid >> 6;
    const int lane = tid & 63;
    const int e = blockIdx.x * 4 + wave;

    const int src = ce[e];
    const int dst = ce[E_ + e];
    const int b = lane >> 3;
    const int hi = (lane & 7) * 16;

    const float4* pps = (const float4*)&ps[((size_t)src * 8 + b) * 128 + hi];
    const float4* ppd = (const float4*)&pd[((size_t)dst * 8 + b) * 128 + hi];

    float partial = 0.f;
#pragma unroll
    for (int q = 0; q < 2; q++) {
        float4 rs = pps[q];
        float4 rd = ppd[q];
        const __half2* hs = (const __half2*)&rs;
        const __half2* hd = (const __half2*)&rd;
#pragma unroll
        for (int j = 0; j < 4; j++) {
            float2 fs = __half22float2(hs[j]);
            float2 fd = __half22float2(hd[j]);
            int idx = hi + q * 8 + j * 2;
            float h0 = fs.x + fd.x + sb1[idx];     h0 = h0 >= 0.f ? h0 : SLOPE * h0;
            float h1 = fs.y + fd.y + sb1[idx + 1]; h1 = h1 >= 0.f ? h1 : SLOPE * h1;
            partial = fmaf(h0, sw2[idx], partial);
            partial = fmaf(h1, sw2[idx + 1], partial);
        }
    }
    partial += __shfl_xor(partial, 1);
    partial += __shfl_xor(partial, 2);
    partial += __shfl_xor(partial, 4);

    if ((lane & 7) == 0) {
        scores[(size_t)b * E_ + e] = (partial + b2[0]) * eattr[e];
    }
}

// ---------------------------------------------------------------- K3a: partial max
__global__ __launch_bounds__(256) void k3a_max(const float* __restrict__ sc,
                                               float* __restrict__ pmax) {
    const int b = blockIdx.y, c = blockIdx.x, tid = threadIdx.x;
    const float* x = sc + (size_t)b * E_;
    const int i0 = c * (E_ / 32);
    float mv = -3.4e38f;
    for (int i = i0 + tid; i < i0 + E_ / 32; i += 256) mv = fmaxf(mv, x[i]);
    __shared__ float red[256];
    red[tid] = mv;
    __syncthreads();
    for (int s = 128; s > 0; s >>= 1) {
        if (tid < s) red[tid] = fmaxf(red[tid], red[tid + s]);
        __syncthreads();
    }
    if (tid == 0) pmax[b * 32 + c] = red[0];
}

// ---------------------------------------------------------------- K3b: final max
__global__ __launch_bounds__(256) void k3b_maxred(const float* __restrict__ pmax,
                                                  float* __restrict__ m) {
    const int t = threadIdx.x;
    float v = pmax[t];
#pragma unroll
    for (int k = 1; k <= 16; k <<= 1) v = fmaxf(v, __shfl_xor(v, k));
    if ((t & 31) == 0) m[t >> 5] = v;
}

// ---------------------------------------------------------------- K3c: partial exp-sums
__global__ __launch_bounds__(256) void k3c_sum(const float* __restrict__ sc,
                                               const float* __restrict__ m,
                                               double* __restrict__ psum) {
    const int b = blockIdx.y, c = blockIdx.x, tid = threadIdx.x;
    const float* x = sc + (size_t)b * E_;
    const float mv = m[b];
    const int i0 = c * (E_ / 32);
    double s = 0.0;
    for (int i = i0 + tid; i < i0 + E_ / 32; i += 256) s += (double)expf(x[i] - mv);
    __shared__ double red[256];
    red[tid] = s;
    __syncthreads();
    for (int st = 128; st > 0; st >>= 1) {
        if (tid < st) red[tid] += red[tid + st];
        __syncthreads();
    }
    if (tid == 0) psum[b * 32 + c] = red[0];
}

// ---------------------------------------------------------------- K3d: final sum -> inv
__global__ __launch_bounds__(256) void k3d_sumred(const double* __restrict__ psum,
                                                  float* __restrict__ inv) {
    const int t = threadIdx.x;
    double v = psum[t];
#pragma unroll
    for (int k = 1; k <= 16; k <<= 1) v += __shfl_xor(v, k);
    if ((t & 31) == 0) inv[t >> 5] = (float)(1.0 / v);
}

// ---------------------------------------------------------------- K3e: normalize + scatter node weights
__global__ __launch_bounds__(256) void k3e_norm_scatter(float* __restrict__ sc,
                                                        const int* __restrict__ ce,
                                                        const unsigned char* __restrict__ cm,
                                                        const float* __restrict__ m,
                                                        const float* __restrict__ inv,
                                                        float* __restrict__ Wm,
                                                        float* __restrict__ Wf) {
    const int e = blockIdx.x * 256 + threadIdx.x;
    const int src = ce[e];
    const int dst = ce[E_ + e];
#pragma unroll
    for (int b = 0; b < 8; b++) {
        float wv = expf(sc[(size_t)b * E_ + e] - m[b]) * inv[b];
        sc[(size_t)b * E_ + e] = wv;  // in-place: scores buffer IS the w output
        atomicAdd(&Wf[b * N_ + dst], wv);
        if (cm[b * N_ + src]) atomicAdd(&Wm[b * N_ + dst], wv);
    }
}

// ---------------------------------------------------------------- K4b: dense weighted sum over X
__global__ __launch_bounds__(256) void k4b_wsum(const float* __restrict__ X,
                                                const float* __restrict__ Wm,
                                                const float* __restrict__ Wf,
                                                float* __restrict__ gpart) {
    const int c = blockIdx.x;
    const int b = blockIdx.y;
    const int tx = threadIdx.x & 63;
    const int ty = threadIdx.x >> 6;
    const int npc = N_ / NCHUNK;
    const int n0 = c * npc;

    const float4* X4 = (const float4*)(X + (size_t)b * N_ * 256);
    float4 am = {0.f, 0.f, 0.f, 0.f};
    float4 af = {0.f, 0.f, 0.f, 0.f};

    for (int n = n0 + ty; n < n0 + npc; n += 4) {
        float wm = Wm[b * N_ + n];
        float wf = Wf[b * N_ + n];
        float4 v = X4[(size_t)n * 64 + tx];
        am.x = fmaf(wm, v.x, am.x); am.y = fmaf(wm, v.y, am.y);
        am.z = fmaf(wm, v.z, am.z); am.w = fmaf(wm, v.w, am.w);
        af.x = fmaf(wf, v.x, af.x); af.y = fmaf(wf, v.y, af.y);
        af.z = fmaf(wf, v.z, af.z); af.w = fmaf(wf, v.w, af.w);
    }

    __shared__ float4 red[256];
    red[threadIdx.x] = am;
    __syncthreads();
    if (ty == 0) {
        float4 r1 = red[tx + 64], r2 = red[tx + 128], r3 = red[tx + 192];
        am.x += r1.x + r2.x + r3.x; am.y += r1.y + r2.y + r3.y;
        am.z += r1.z + r2.z + r3.z; am.w += r1.w + r2.w + r3.w;
    }
    __syncthreads();
    red[threadIdx.x] = af;
    __syncthreads();
    if (ty == 0) {
        float4 r1 = red[tx + 64], r2 = red[tx + 128], r3 = red[tx + 192];
        af.x += r1.x + r2.x + r3.x; af.y += r1.y + r2.y + r3.y;
        af.z += r1.z + r2.z + r3.z; af.w += r1.w + r2.w + r3.w;
        float4* gp4 = (float4*)gpart;
        gp4[((c * 2 + 0) * 8 + b) * 64 + tx] = am;
        gp4[((c * 2 + 1) * 8 + b) * 64 + tx] = af;
    }
}

// ---------------------------------------------------------------- K5: finalize
__global__ __launch_bounds__(256) void k5_final(const float* __restrict__ gpart,
                                                const float* __restrict__ cnt,
                                                float* __restrict__ gf) {
    const int b = blockIdx.x;
    const int d = threadIdx.x;
    float sm = 0.f, sf = 0.f;
    for (int c = 0; c < NCHUNK; c++) {
        sm += gpart[((c * 2 + 0) * 8 + b) * 256 + d];
        sf += gpart[((c * 2 + 1) * 8 + b) * 256 + d];
    }
    const float cn = cnt[b];
    gf[b * 256 + d] = (cn > 0.f) ? (sm / cn) : (sf / (float)N_);
}

// ---------------------------------------------------------------- launch
extern "C" void kernel_launch(void* const* d_in, const int* in_sizes, int n_in,
                              void* d_out, int out_size, void* d_ws, size_t ws_size,
                              hipStream_t stream) {
    const float* X     = (const float*)d_in[0];
    const float* eattr = (const float*)d_in[1];
    const float* W1    = (const float*)d_in[2];
    const float* b1    = (const float*)d_in[3];
    const float* W2    = (const float*)d_in[4];
    const float* b2    = (const float*)d_in[5];
    const int*   eidx_raw = (const int*)d_in[6];
    const unsigned char* mask8 = (const unsigned char*)d_in[7];
    const unsigned int*  mask32 = (const unsigned int*)d_in[7];

    float* out  = (float*)d_out;
    float* gf   = out;          // [B,D]
    float* wout = out + 2048;   // [B,E]: scores -> softmaxed w in place

    __half* ps_h = (__half*)d_ws;                         // [N*8*128] fp16
    __half* pd_h = ps_h + (size_t)N_ * 8 * 128;
    __half* Wt   = pd_h + (size_t)N_ * 8 * 128;           // [2*128*256] fp16
    int* ce = (int*)(Wt + 2 * 128 * 256);                 // [2E]
    unsigned char* cm = (unsigned char*)(ce + 2 * E_);    // [B*N]
    float* Wm  = (float*)(cm + B_ * N_);                  // [B*N]
    float* Wf  = Wm + B_ * N_;                            // [B*N]
    float* cnt = Wf + B_ * N_;                            // [8]
    int* flags = (int*)(cnt + 8);                         // [2]
    float* pmax = (float*)(flags + 2);                    // [256]
    float* mbuf = pmax + 256;                             // [8]
    float* invb = mbuf + 8;                               // [8]
    double* psum = (double*)(((uintptr_t)(invb + 8) + 15) & ~(uintptr_t)15);  // [256]
    float* gpart = (float*)(psum + 256);                  // [NCHUNK*2*8*256]

    hipLaunchKernelGGL(k_detect, dim3(1), dim3(64), 0, stream, eidx_raw, mask32, flags);
    hipLaunchKernelGGL(k_canon, dim3(1250), dim3(256), 0, stream,
                       eidx_raw, mask8, mask32, flags, ce, cm, Wm);
    hipLaunchKernelGGL(kW, dim3(256), dim3(256), 0, stream, W1, Wt);
    hipLaunchKernelGGL(k0_init, dim3(8), dim3(256), 0, stream, cm, cnt);
    hipLaunchKernelGGL(k1_mfma, dim3(625, 2), dim3(256), 0, stream, X, Wt, ps_h, pd_h);
    hipLaunchKernelGGL(k2_scores, dim3(E_ / 4), dim3(256), 0, stream,
                       ps_h, pd_h, ce, b1, W2, b2, eattr, wout);
    hipLaunchKernelGGL(k3a_max, dim3(32, 8), dim3(256), 0, stream, wout, pmax);
    hipLaunchKernelGGL(k3b_maxred, dim3(1), dim3(256), 0, stream, pmax, mbuf);
    hipLaunchKernelGGL(k3c_sum, dim3(32, 8), dim3(256), 0, stream, wout, mbuf, psum);
    hipLaunchKernelGGL(k3d_sumred, dim3(1), dim3(256), 0, stream, psum, invb);
    hipLaunchKernelGGL(k3e_norm_scatter, dim3(E_ / 256), dim3(256), 0, stream,
                       wout, ce, cm, mbuf, invb, Wm, Wf);
    hipLaunchKernelGGL(k4b_wsum, dim3(NCHUNK, 8), dim3(256), 0, stream, X, Wm, Wf, gpart);
    hipLaunchKernelGGL(k5_final, dim3(8), dim3(256), 0, stream, gpart, cnt, gf);
}

// Round 5
// 326.012 us; speedup vs baseline: 2.1002x; 1.2210x over previous
//
#include <hip/hip_runtime.h>
#include <hip/hip_bf16.h>
#include <hip/hip_fp16.h>

#define B_ 8
#define N_ 10000
#define E_ 160000
#define D_ 256
#define H_ 128
#define SLOPE 0.2f
#define NCHUNK 50   // node chunks for dense weighted sum (200 nodes/chunk)

// binning config
#define EC_ 16            // edge chunks
#define NR_ 32            // node ranges
#define RANGE_ 320        // nodes per range
#define NPAD_ (NR_ * RANGE_)   // 10240 padded nodes

typedef __attribute__((ext_vector_type(8))) _Float16 v8h;
typedef __attribute__((ext_vector_type(4))) _Float16 v4h;
typedef __attribute__((ext_vector_type(4))) float f32x4;

// ---------------------------------------------------------------- K-detect
__global__ __launch_bounds__(64) void k_detect(const int* __restrict__ eidx_raw,
                                               const unsigned int* __restrict__ mask32,
                                               int* __restrict__ flags) {
    const int t = threadIdx.x;
    unsigned long long oddnz = __ballot(eidx_raw[2 * t + 1] != 0);
    unsigned long long mgt1  = __ballot(mask32[t] > 1u);
    if (t == 0) {
        flags[0] = (oddnz == 0ull) ? 1 : 0;  // edge_index is int64
        flags[1] = (mgt1 != 0ull) ? 1 : 0;   // mask is 1-byte bool
    }
}

// ---------------------------------------------------------------- K-canon
// edge_index->int32 ce[2E]; mask -> cm[b*N+n] (batch-major) and cmT[n*8+b]
__global__ __launch_bounds__(256) void k_canon(const int* __restrict__ eidx_raw,
                                               const unsigned char* __restrict__ mask8,
                                               const unsigned int* __restrict__ mask32,
                                               const int* __restrict__ flags,
                                               int* __restrict__ ce,
                                               unsigned char* __restrict__ cm,
                                               unsigned char* __restrict__ cmT) {
    const int i = blockIdx.x * 256 + threadIdx.x;
    const int f_e = flags[0], f_m = flags[1];
    if (i < 2 * E_) ce[i] = f_e ? eidx_raw[2 * i] : eidx_raw[i];
    if (i < B_ * N_) {
        unsigned char v = f_m ? (unsigned char)(mask8[i] != 0)
                              : (unsigned char)(mask32[i] != 0u);
        cm[i] = v;
        const int b = i / N_;
        const int n = i - b * N_;
        cmT[n * 8 + b] = v;
    }
}

// ---------------------------------------------------------------- kW: W1 -> fp16 transposed
__global__ __launch_bounds__(256) void kW(const float* __restrict__ W1,
                                          __half* __restrict__ Wt) {
    const int i = blockIdx.x * 256 + threadIdx.x;  // 0..65535
    const int f = i & 127;
    const int row = i >> 7;       // 0..511
    const int c = row >> 8, k = row & 255;
    Wt[((c * 128 + f) * 256) + k] = __float2half(W1[row * 128 + f]);
}

// ---------------------------------------------------------------- K0: count valid nodes
__global__ __launch_bounds__(256) void k0_init(const unsigned char* __restrict__ cm,
                                               float* __restrict__ cnt) {
    const int b = blockIdx.x;
    const int tid = threadIdx.x;
    int c = 0;
    for (int i = tid; i < N_; i += 256) c += cm[b * N_ + i] ? 1 : 0;
    __shared__ int red[256];
    red[tid] = c;
    __syncthreads();
    for (int s = 128; s > 0; s >>= 1) {
        if (tid < s) red[tid] += red[tid + s];
        __syncthreads();
    }
    if (tid == 0) cnt[b] = (float)red[0];
}

// ---------------------------------------------------------------- K1: MFMA projection GEMM
__global__ __launch_bounds__(256) void k1_mfma(const float* __restrict__ X,
                                               const __half* __restrict__ Wt,
                                               __half* __restrict__ ps,
                                               __half* __restrict__ pd) {
    const int cb = blockIdx.y;
    const int rb = blockIdx.x;
    const int tid = threadIdx.x;
    const int wave = tid >> 6, lane = tid & 63;
    const int quad = lane >> 4, l16 = lane & 15;

    __shared__ _Float16 Xs[128 * 40];
    __shared__ _Float16 Ws[128 * 40];

    f32x4 acc[2][8];
#pragma unroll
    for (int i = 0; i < 2; i++)
#pragma unroll
        for (int j = 0; j < 8; j++) acc[i][j] = (f32x4){0.f, 0.f, 0.f, 0.f};

    const int row_base = rb * 128;
    const __half* __restrict__ Wh = Wt + (size_t)cb * 128 * 256;
    __half* __restrict__ outp = cb ? pd : ps;

    const int sr = tid >> 1;
    const int sh = tid & 1;

    for (int kc = 0; kc < 8; ++kc) {
        {
            const float4* src = (const float4*)&X[(size_t)(row_base + sr) * 256 + kc * 32 + sh * 16];
            _Float16* dst = &Xs[sr * 40 + sh * 16];
#pragma unroll
            for (int j = 0; j < 4; ++j) {
                float4 v = src[j];
                v4h p = {(_Float16)v.x, (_Float16)v.y, (_Float16)v.z, (_Float16)v.w};
                *(v4h*)&dst[j * 4] = p;
            }
        }
        {
            const float4* src = (const float4*)&Wh[(size_t)sr * 256 + kc * 32 + sh * 16];
            float4 v0 = src[0], v1 = src[1];
            *(float4*)&Ws[sr * 40 + sh * 16] = v0;
            *(float4*)&Ws[sr * 40 + sh * 16 + 8] = v1;
        }
        __syncthreads();

        v8h wf[2];
#pragma unroll
        for (int ft = 0; ft < 2; ++ft)
            wf[ft] = *(v8h*)&Ws[(wave * 32 + ft * 16 + l16) * 40 + quad * 8];
#pragma unroll
        for (int nt = 0; nt < 8; ++nt) {
            v8h xf = *(v8h*)&Xs[(nt * 16 + l16) * 40 + quad * 8];
            acc[0][nt] = __builtin_amdgcn_mfma_f32_16x16x32_f16(wf[0], xf, acc[0][nt], 0, 0, 0);
            acc[1][nt] = __builtin_amdgcn_mfma_f32_16x16x32_f16(wf[1], xf, acc[1][nt], 0, 0, 0);
        }
        __syncthreads();
    }

#pragma unroll
    for (int nt = 0; nt < 8; ++nt) {
        const int R = row_base + nt * 16 + l16;
        const int b = R / N_;
        const int n = R - b * N_;
        __half* base = outp + ((size_t)(n * 8 + b)) * 128 + wave * 32 + quad * 4;
#pragma unroll
        for (int ft = 0; ft < 2; ++ft) {
            f32x4 a = acc[ft][nt];
            v4h h = {(_Float16)a.x, (_Float16)a.y, (_Float16)a.z, (_Float16)a.w};
            *(v4h*)(base + ft * 16) = h;
        }
    }
}

// ---------------------------------------------------------------- K2: edge scores (fp16 gathers)
__global__ __launch_bounds__(256) void k2_scores(const __half* __restrict__ ps,
                                                 const __half* __restrict__ pd,
                                                 const int* __restrict__ ce,
                                                 const float* __restrict__ b1,
                                                 const float* __restrict__ W2,
                                                 const float* __restrict__ b2,
                                                 const float* __restrict__ eattr,
                                                 float* __restrict__ scores) {
    __shared__ float sb1[128];
    __shared__ float sw2[128];
    const int tid = threadIdx.x;
    if (tid < 128) sb1[tid] = b1[tid];
    else sw2[tid - 128] = W2[tid - 128];
    __syncthreads();

    const int wave = tid >> 6;
    const int lane = tid & 63;
    const int e = blockIdx.x * 4 + wave;

    const int src = ce[e];
    const int dst = ce[E_ + e];
    const int b = lane >> 3;
    const int hi = (lane & 7) * 16;

    const float4* pps = (const float4*)&ps[((size_t)src * 8 + b) * 128 + hi];
    const float4* ppd = (const float4*)&pd[((size_t)dst * 8 + b) * 128 + hi];

    float partial = 0.f;
#pragma unroll
    for (int q = 0; q < 2; q++) {
        float4 rs = pps[q];
        float4 rd = ppd[q];
        const __half2* hs = (const __half2*)&rs;
        const __half2* hd = (const __half2*)&rd;
#pragma unroll
        for (int j = 0; j < 4; j++) {
            float2 fs = __half22float2(hs[j]);
            float2 fd = __half22float2(hd[j]);
            int idx = hi + q * 8 + j * 2;
            float h0 = fs.x + fd.x + sb1[idx];     h0 = h0 >= 0.f ? h0 : SLOPE * h0;
            float h1 = fs.y + fd.y + sb1[idx + 1]; h1 = h1 >= 0.f ? h1 : SLOPE * h1;
            partial = fmaf(h0, sw2[idx], partial);
            partial = fmaf(h1, sw2[idx + 1], partial);
        }
    }
    partial += __shfl_xor(partial, 1);
    partial += __shfl_xor(partial, 2);
    partial += __shfl_xor(partial, 4);

    if ((lane & 7) == 0) {
        scores[(size_t)b * E_ + e] = (partial + b2[0]) * eattr[e];
    }
}

// ---------------------------------------------------------------- K3a: partial max
__global__ __launch_bounds__(256) void k3a_max(const float* __restrict__ sc,
                                               float* __restrict__ pmax) {
    const int b = blockIdx.y, c = blockIdx.x, tid = threadIdx.x;
    const float* x = sc + (size_t)b * E_;
    const int i0 = c * (E_ / 32);
    float mv = -3.4e38f;
    for (int i = i0 + tid; i < i0 + E_ / 32; i += 256) mv = fmaxf(mv, x[i]);
    __shared__ float red[256];
    red[tid] = mv;
    __syncthreads();
    for (int s = 128; s > 0; s >>= 1) {
        if (tid < s) red[tid] = fmaxf(red[tid], red[tid + s]);
        __syncthreads();
    }
    if (tid == 0) pmax[b * 32 + c] = red[0];
}

// ---------------------------------------------------------------- K3b: final max
__global__ __launch_bounds__(256) void k3b_maxred(const float* __restrict__ pmax,
                                                  float* __restrict__ m) {
    const int t = threadIdx.x;
    float v = pmax[t];
#pragma unroll
    for (int k = 1; k <= 16; k <<= 1) v = fmaxf(v, __shfl_xor(v, k));
    if ((t & 31) == 0) m[t >> 5] = v;
}

// ---------------------------------------------------------------- K3c: partial exp-sums
__global__ __launch_bounds__(256) void k3c_sum(const float* __restrict__ sc,
                                               const float* __restrict__ m,
                                               double* __restrict__ psum) {
    const int b = blockIdx.y, c = blockIdx.x, tid = threadIdx.x;
    const float* x = sc + (size_t)b * E_;
    const float mv = m[b];
    const int i0 = c * (E_ / 32);
    double s = 0.0;
    for (int i = i0 + tid; i < i0 + E_ / 32; i += 256) s += (double)expf(x[i] - mv);
    __shared__ double red[256];
    red[tid] = s;
    __syncthreads();
    for (int st = 128; st > 0; st >>= 1) {
        if (tid < st) red[tid] += red[tid + st];
        __syncthreads();
    }
    if (tid == 0) psum[b * 32 + c] = red[0];
}

// ---------------------------------------------------------------- K3d: final sum -> inv
__global__ __launch_bounds__(256) void k3d_sumred(const double* __restrict__ psum,
                                                  float* __restrict__ inv) {
    const int t = threadIdx.x;
    double v = psum[t];
#pragma unroll
    for (int k = 1; k <= 16; k <<= 1) v += __shfl_xor(v, k);
    if ((t & 31) == 0) inv[t >> 5] = (float)(1.0 / v);
}

// ---------------------------------------------------------------- K3e: normalize w, write wT[e][8]
__global__ __launch_bounds__(256) void k3e_norm(float* __restrict__ sc,
                                                const float* __restrict__ m,
                                                const float* __restrict__ inv,
                                                float* __restrict__ wT) {
    const int e = blockIdx.x * 256 + threadIdx.x;
    float wv[8];
#pragma unroll
    for (int b = 0; b < 8; b++) {
        float v = expf(sc[(size_t)b * E_ + e] - m[b]) * inv[b];
        sc[(size_t)b * E_ + e] = v;  // in-place: scores buffer IS the w output
        wv[b] = v;
    }
    *(float4*)&wT[(size_t)e * 8]     = make_float4(wv[0], wv[1], wv[2], wv[3]);
    *(float4*)&wT[(size_t)e * 8 + 4] = make_float4(wv[4], wv[5], wv[6], wv[7]);
}

// ---------------------------------------------------------------- K3f: LDS-binned node-weight accumulation
// grid (EC_, NR_); block privately accumulates nodes [rg*RANGE_, +RANGE_) over
// edges [ec*E/EC_, +E/EC_) in LDS, then writes its partial non-atomically.
__global__ __launch_bounds__(256) void k3f_bin(const int* __restrict__ ce,
                                               const float* __restrict__ wT,
                                               const unsigned char* __restrict__ cmT,
                                               float* __restrict__ Wpart) {
    const int ec = blockIdx.x;
    const int rg = blockIdx.y;
    const int n0 = rg * RANGE_;

    __shared__ float lWf[RANGE_ * 8];
    __shared__ float lWm[RANGE_ * 8];
    for (int i = threadIdx.x; i < RANGE_ * 8; i += 256) { lWf[i] = 0.f; lWm[i] = 0.f; }
    __syncthreads();

    const int4* dst4 = (const int4*)(ce + E_);
    const int base4 = ec * (E_ / EC_ / 4);   // 2500 int4 per chunk
    for (int i = threadIdx.x; i < E_ / EC_ / 4; i += 256) {
        int4 d4 = dst4[base4 + i];
        int dd[4] = {d4.x, d4.y, d4.z, d4.w};
        const int e0 = (base4 + i) * 4;
#pragma unroll
        for (int j = 0; j < 4; ++j) {
            const int rel = dd[j] - n0;
            if ((unsigned)rel < (unsigned)RANGE_) {
                const int e = e0 + j;
                const int src = ce[e];
                float4 w0 = *(const float4*)&wT[(size_t)e * 8];
                float4 w1 = *(const float4*)&wT[(size_t)e * 8 + 4];
                const unsigned long long mm = *(const unsigned long long*)&cmT[src * 8];
                float wv[8] = {w0.x, w0.y, w0.z, w0.w, w1.x, w1.y, w1.z, w1.w};
                float* lf = &lWf[rel * 8];
                float* lm = &lWm[rel * 8];
#pragma unroll
                for (int b = 0; b < 8; b++) {
                    atomicAdd(&lf[b], wv[b]);
                    if ((mm >> (8 * b)) & 1ull) atomicAdd(&lm[b], wv[b]);
                }
            }
        }
    }
    __syncthreads();

    float* of = Wpart + ((size_t)ec * 2 + 0) * (NPAD_ * 8) + n0 * 8;
    float* om = Wpart + ((size_t)ec * 2 + 1) * (NPAD_ * 8) + n0 * 8;
    for (int i = threadIdx.x; i < RANGE_ * 8; i += 256) { of[i] = lWf[i]; om[i] = lWm[i]; }
}

// ---------------------------------------------------------------- K3g: reduce partials -> WfT/WmT [n][8]
__global__ __launch_bounds__(256) void k3g_reduce(const float* __restrict__ Wpart,
                                                  float* __restrict__ WfT,
                                                  float* __restrict__ WmT) {
    const int i = blockIdx.x * 256 + threadIdx.x;  // < NPAD_*8
    float sf = 0.f, sm = 0.f;
#pragma unroll
    for (int ec = 0; ec < EC_; ec++) {
        sf += Wpart[(size_t)ec * 2 * (NPAD_ * 8) + i];
        sm += Wpart[((size_t)ec * 2 + 1) * (NPAD_ * 8) + i];
    }
    WfT[i] = sf;
    WmT[i] = sm;
}

// ---------------------------------------------------------------- K4b: dense weighted sum over X
__global__ __launch_bounds__(256) void k4b_wsum(const float* __restrict__ X,
                                                const float* __restrict__ WmT,
                                                const float* __restrict__ WfT,
                                                float* __restrict__ gpart) {
    const int c = blockIdx.x;
    const int b = blockIdx.y;
    const int tx = threadIdx.x & 63;
    const int ty = threadIdx.x >> 6;
    const int npc = N_ / NCHUNK;
    const int n0 = c * npc;

    const float4* X4 = (const float4*)(X + (size_t)b * N_ * 256);
    float4 am = {0.f, 0.f, 0.f, 0.f};
    float4 af = {0.f, 0.f, 0.f, 0.f};

    for (int n = n0 + ty; n < n0 + npc; n += 4) {
        float wm = WmT[n * 8 + b];
        float wf = WfT[n * 8 + b];
        float4 v = X4[(size_t)n * 64 + tx];
        am.x = fmaf(wm, v.x, am.x); am.y = fmaf(wm, v.y, am.y);
        am.z = fmaf(wm, v.z, am.z); am.w = fmaf(wm, v.w, am.w);
        af.x = fmaf(wf, v.x, af.x); af.y = fmaf(wf, v.y, af.y);
        af.z = fmaf(wf, v.z, af.z); af.w = fmaf(wf, v.w, af.w);
    }

    __shared__ float4 red[256];
    red[threadIdx.x] = am;
    __syncthreads();
    if (ty == 0) {
        float4 r1 = red[tx + 64], r2 = red[tx + 128], r3 = red[tx + 192];
        am.x += r1.x + r2.x + r3.x; am.y += r1.y + r2.y + r3.y;
        am.z += r1.z + r2.z + r3.z; am.w += r1.w + r2.w + r3.w;
    }
    __syncthreads();
    red[threadIdx.x] = af;
    __syncthreads();
    if (ty == 0) {
        float4 r1 = red[tx + 64], r2 = red[tx + 128], r3 = red[tx + 192];
        af.x += r1.x + r2.x + r3.x; af.y += r1.y + r2.y + r3.y;
        af.z += r1.z + r2.z + r3.z; af.w += r1.w + r2.w + r3.w;
        float4* gp4 = (float4*)gpart;
        gp4[((c * 2 + 0) * 8 + b) * 64 + tx] = am;
        gp4[((c * 2 + 1) * 8 + b) * 64 + tx] = af;
    }
}

// ---------------------------------------------------------------- K5: finalize
__global__ __launch_bounds__(256) void k5_final(const float* __restrict__ gpart,
                                                const float* __restrict__ cnt,
                                                float* __restrict__ gf) {
    const int b = blockIdx.x;
    const int d = threadIdx.x;
    float sm = 0.f, sf = 0.f;
    for (int c = 0; c < NCHUNK; c++) {
        sm += gpart[((c * 2 + 0) * 8 + b) * 256 + d];
        sf += gpart[((c * 2 + 1) * 8 + b) * 256 + d];
    }
    const float cn = cnt[b];
    gf[b * 256 + d] = (cn > 0.f) ? (sm / cn) : (sf / (float)N_);
}

// ---------------------------------------------------------------- launch
extern "C" void kernel_launch(void* const* d_in, const int* in_sizes, int n_in,
                              void* d_out, int out_size, void* d_ws, size_t ws_size,
                              hipStream_t stream) {
    const float* X     = (const float*)d_in[0];
    const float* eattr = (const float*)d_in[1];
    const float* W1    = (const float*)d_in[2];
    const float* b1    = (const float*)d_in[3];
    const float* W2    = (const float*)d_in[4];
    const float* b2    = (const float*)d_in[5];
    const int*   eidx_raw = (const int*)d_in[6];
    const unsigned char* mask8 = (const unsigned char*)d_in[7];
    const unsigned int*  mask32 = (const unsigned int*)d_in[7];

    float* out  = (float*)d_out;
    float* gf   = out;          // [B,D]
    float* wout = out + 2048;   // [B,E]: scores -> softmaxed w in place

    // persistent region
    __half* ps_h = (__half*)d_ws;                         // [N*8*128] fp16 (20.48 MB)
    __half* pd_h = ps_h + (size_t)N_ * 8 * 128;           // [N*8*128] fp16
    __half* Wt   = pd_h + (size_t)N_ * 8 * 128;           // [2*128*256] fp16
    int* ce = (int*)(Wt + 2 * 128 * 256);                 // [2E]
    unsigned char* cmT = (unsigned char*)(ce + 2 * E_);   // [NPAD_*8] (node-major mask)
    unsigned char* cm  = cmT + NPAD_ * 8;                 // [B*N] (batch-major mask)
    float* cnt = (float*)(cm + B_ * N_);                  // [8]
    int* flags = (int*)(cnt + 8);                         // [2]
    float* pmax = (float*)(flags + 2);                    // [256]
    float* mbuf = pmax + 256;                             // [8]
    float* invb = mbuf + 8;                               // [8]
    double* psum = (double*)(((uintptr_t)(invb + 8) + 15) & ~(uintptr_t)15);  // [256]
    float* gpart = (float*)(psum + 256);                  // [NCHUNK*2*8*256]

    // overlay region (reuses ps_h: dead after k2_scores) — 16.3 MB < 20.48 MB
    float* wT    = (float*)d_ws;                          // [E*8]
    float* Wpart = wT + (size_t)E_ * 8;                   // [EC_*2*NPAD_*8]
    float* WfT   = Wpart + (size_t)EC_ * 2 * NPAD_ * 8;   // [NPAD_*8]
    float* WmT   = WfT + NPAD_ * 8;                       // [NPAD_*8]

    hipLaunchKernelGGL(k_detect, dim3(1), dim3(64), 0, stream, eidx_raw, mask32, flags);
    hipLaunchKernelGGL(k_canon, dim3(1250), dim3(256), 0, stream,
                       eidx_raw, mask8, mask32, flags, ce, cm, cmT);
    hipLaunchKernelGGL(kW, dim3(256), dim3(256), 0, stream, W1, Wt);
    hipLaunchKernelGGL(k0_init, dim3(8), dim3(256), 0, stream, cm, cnt);
    hipLaunchKernelGGL(k1_mfma, dim3(625, 2), dim3(256), 0, stream, X, Wt, ps_h, pd_h);
    hipLaunchKernelGGL(k2_scores, dim3(E_ / 4), dim3(256), 0, stream,
                       ps_h, pd_h, ce, b1, W2, b2, eattr, wout);
    hipLaunchKernelGGL(k3a_max, dim3(32, 8), dim3(256), 0, stream, wout, pmax);
    hipLaunchKernelGGL(k3b_maxred, dim3(1), dim3(256), 0, stream, pmax, mbuf);
    hipLaunchKernelGGL(k3c_sum, dim3(32, 8), dim3(256), 0, stream, wout, mbuf, psum);
    hipLaunchKernelGGL(k3d_sumred, dim3(1), dim3(256), 0, stream, psum, invb);
    hipLaunchKernelGGL(k3e_norm, dim3(E_ / 256), dim3(256), 0, stream,
                       wout, mbuf, invb, wT);
    hipLaunchKernelGGL(k3f_bin, dim3(EC_, NR_), dim3(256), 0, stream, ce, wT, cmT, Wpart);
    hipLaunchKernelGGL(k3g_reduce, dim3(NPAD_ * 8 / 256), dim3(256), 0, stream,
                       Wpart, WfT, WmT);
    hipLaunchKernelGGL(k4b_wsum, dim3(NCHUNK, 8), dim3(256), 0, stream, X, WmT, WfT, gpart);
    hipLaunchKernelGGL(k5_final, dim3(8), dim3(256), 0, stream, gpart, cnt, gf);
}

// Round 6
// 324.485 us; speedup vs baseline: 2.1101x; 1.0047x over previous
//
#include <hip/hip_runtime.h>
#include <hip/hip_bf16.h>
#include <hip/hip_fp16.h>

#define B_ 8
#define N_ 10000
#define E_ 160000
#define D_ 256
#define H_ 128
#define SLOPE 0.2f
#define NCHUNK 50   // node chunks for dense weighted sum (200 nodes/chunk)

// binning config (node-weight accumulation)
#define EC_ 16            // edge chunks
#define NR_ 32            // node ranges
#define RANGE_ 320        // nodes per range
#define NPAD_ (NR_ * RANGE_)   // 10240 padded nodes

// edge-sort config (k2 locality)
#define NB_ 64            // histogram/scatter blocks
#define EPB_ (E_ / NB_)   // 2500 edges per block
#define BINS_ 256         // 16 dst-buckets x 16 src-buckets
#define NPB_ (N_ / 16)    // 625 nodes per bucket

typedef __attribute__((ext_vector_type(8))) _Float16 v8h;
typedef __attribute__((ext_vector_type(4))) _Float16 v4h;
typedef __attribute__((ext_vector_type(2))) _Float16 v2h;
typedef __attribute__((ext_vector_type(4))) float f32x4;

static __device__ __forceinline__ float dot2f(v2h a, v2h b, float c) {
#if __has_builtin(__builtin_amdgcn_fdot2)
    return __builtin_amdgcn_fdot2(a, b, c, false);
#else
    return fmaf((float)a.y, (float)b.y, fmaf((float)a.x, (float)b.x, c));
#endif
}

// ---------------------------------------------------------------- K-detect
__global__ __launch_bounds__(64) void k_detect(const int* __restrict__ eidx_raw,
                                               const unsigned int* __restrict__ mask32,
                                               int* __restrict__ flags) {
    const int t = threadIdx.x;
    unsigned long long oddnz = __ballot(eidx_raw[2 * t + 1] != 0);
    unsigned long long mgt1  = __ballot(mask32[t] > 1u);
    if (t == 0) {
        flags[0] = (oddnz == 0ull) ? 1 : 0;  // edge_index is int64
        flags[1] = (mgt1 != 0ull) ? 1 : 0;   // mask is 1-byte bool
    }
}

// ---------------------------------------------------------------- K-canon
__global__ __launch_bounds__(256) void k_canon(const int* __restrict__ eidx_raw,
                                               const unsigned char* __restrict__ mask8,
                                               const unsigned int* __restrict__ mask32,
                                               const int* __restrict__ flags,
                                               int* __restrict__ ce,
                                               unsigned char* __restrict__ cm,
                                               unsigned char* __restrict__ cmT) {
    const int i = blockIdx.x * 256 + threadIdx.x;
    const int f_e = flags[0], f_m = flags[1];
    if (i < 2 * E_) ce[i] = f_e ? eidx_raw[2 * i] : eidx_raw[i];
    if (i < B_ * N_) {
        unsigned char v = f_m ? (unsigned char)(mask8[i] != 0)
                              : (unsigned char)(mask32[i] != 0u);
        cm[i] = v;
        const int b = i / N_;
        const int n = i - b * N_;
        cmT[n * 8 + b] = v;
    }
}

// ---------------------------------------------------------------- kW: W1 -> fp16 transposed; b1/W2 -> fp16
__global__ __launch_bounds__(256) void kW(const float* __restrict__ W1,
                                          const float* __restrict__ b1,
                                          const float* __restrict__ W2,
                                          __half* __restrict__ Wt,
                                          __half* __restrict__ b1h,
                                          __half* __restrict__ w2h) {
    const int i = blockIdx.x * 256 + threadIdx.x;  // 0..65535
    const int f = i & 127;
    const int row = i >> 7;       // 0..511
    const int c = row >> 8, k = row & 255;
    Wt[((c * 128 + f) * 256) + k] = __float2half(W1[row * 128 + f]);
    if (blockIdx.x == 0 && threadIdx.x < 128) {
        b1h[threadIdx.x] = __float2half(b1[threadIdx.x]);
        w2h[threadIdx.x] = __float2half(W2[threadIdx.x]);
    }
}

// ---------------------------------------------------------------- K0: count valid nodes
__global__ __launch_bounds__(256) void k0_init(const unsigned char* __restrict__ cm,
                                               float* __restrict__ cnt) {
    const int b = blockIdx.x;
    const int tid = threadIdx.x;
    int c = 0;
    for (int i = tid; i < N_; i += 256) c += cm[b * N_ + i] ? 1 : 0;
    __shared__ int red[256];
    red[tid] = c;
    __syncthreads();
    for (int s = 128; s > 0; s >>= 1) {
        if (tid < s) red[tid] += red[tid + s];
        __syncthreads();
    }
    if (tid == 0) cnt[b] = (float)red[0];
}

// ---------------------------------------------------------------- edge sort: histogram
__global__ __launch_bounds__(256) void khist(const int* __restrict__ ce,
                                             int* __restrict__ hpart) {
    __shared__ int h[BINS_];
    const int tid = threadIdx.x;
    h[tid] = 0;
    __syncthreads();
    const int base = blockIdx.x * EPB_;
    for (int i = tid; i < EPB_; i += 256) {
        const int s = ce[base + i], d = ce[E_ + base + i];
        const int bin = (d / NPB_) * 16 + s / NPB_;
        atomicAdd(&h[bin], 1);
    }
    __syncthreads();
    hpart[blockIdx.x * BINS_ + tid] = h[tid];
}

// ---------------------------------------------------------------- edge sort: prefix
__global__ __launch_bounds__(256) void kprefix(const int* __restrict__ hpart,
                                               int* __restrict__ offsetG) {
    __shared__ int cnt[BINS_];
    __shared__ int excl[BINS_];
    const int bin = threadIdx.x;
    int c = 0;
    for (int b = 0; b < NB_; b++) c += hpart[b * BINS_ + bin];
    cnt[bin] = c;
    __syncthreads();
    if (bin == 0) {
        int r = 0;
        for (int i = 0; i < BINS_; i++) { excl[i] = r; r += cnt[i]; }
    }
    __syncthreads();
    int run = excl[bin];
    for (int b = 0; b < NB_; b++) {
        offsetG[b * BINS_ + bin] = run;
        run += hpart[b * BINS_ + bin];
    }
}

// ---------------------------------------------------------------- edge sort: scatter
__global__ __launch_bounds__(256) void kscatter(const int* __restrict__ ce,
                                                const int* __restrict__ offsetG,
                                                int* __restrict__ srcS,
                                                int* __restrict__ dstS,
                                                int* __restrict__ origS) {
    __shared__ int loc[BINS_];
    const int tid = threadIdx.x;
    loc[tid] = offsetG[blockIdx.x * BINS_ + tid];
    __syncthreads();
    const int base = blockIdx.x * EPB_;
    for (int i = tid; i < EPB_; i += 256) {
        const int e = base + i;
        const int s = ce[e], d = ce[E_ + e];
        const int bin = (d / NPB_) * 16 + s / NPB_;
        const int pos = atomicAdd(&loc[bin], 1);
        srcS[pos] = s;
        dstS[pos] = d;
        origS[pos] = e;
    }
}

// ---------------------------------------------------------------- K1: MFMA projection GEMM
__global__ __launch_bounds__(256) void k1_mfma(const float* __restrict__ X,
                                               const __half* __restrict__ Wt,
                                               __half* __restrict__ ps,
                                               __half* __restrict__ pd) {
    const int cb = blockIdx.y;
    const int rb = blockIdx.x;
    const int tid = threadIdx.x;
    const int wave = tid >> 6, lane = tid & 63;
    const int quad = lane >> 4, l16 = lane & 15;

    __shared__ _Float16 Xs[128 * 40];
    __shared__ _Float16 Ws[128 * 40];

    f32x4 acc[2][8];
#pragma unroll
    for (int i = 0; i < 2; i++)
#pragma unroll
        for (int j = 0; j < 8; j++) acc[i][j] = (f32x4){0.f, 0.f, 0.f, 0.f};

    const int row_base = rb * 128;
    const __half* __restrict__ Wh = Wt + (size_t)cb * 128 * 256;
    __half* __restrict__ outp = cb ? pd : ps;

    const int sr = tid >> 1;
    const int sh = tid & 1;

    for (int kc = 0; kc < 8; ++kc) {
        {
            const float4* src = (const float4*)&X[(size_t)(row_base + sr) * 256 + kc * 32 + sh * 16];
            _Float16* dst = &Xs[sr * 40 + sh * 16];
#pragma unroll
            for (int j = 0; j < 4; ++j) {
                float4 v = src[j];
                v4h p = {(_Float16)v.x, (_Float16)v.y, (_Float16)v.z, (_Float16)v.w};
                *(v4h*)&dst[j * 4] = p;
            }
        }
        {
            const float4* src = (const float4*)&Wh[(size_t)sr * 256 + kc * 32 + sh * 16];
            float4 v0 = src[0], v1 = src[1];
            *(float4*)&Ws[sr * 40 + sh * 16] = v0;
            *(float4*)&Ws[sr * 40 + sh * 16 + 8] = v1;
        }
        __syncthreads();

        v8h wf[2];
#pragma unroll
        for (int ft = 0; ft < 2; ++ft)
            wf[ft] = *(v8h*)&Ws[(wave * 32 + ft * 16 + l16) * 40 + quad * 8];
#pragma unroll
        for (int nt = 0; nt < 8; ++nt) {
            v8h xf = *(v8h*)&Xs[(nt * 16 + l16) * 40 + quad * 8];
            acc[0][nt] = __builtin_amdgcn_mfma_f32_16x16x32_f16(wf[0], xf, acc[0][nt], 0, 0, 0);
            acc[1][nt] = __builtin_amdgcn_mfma_f32_16x16x32_f16(wf[1], xf, acc[1][nt], 0, 0, 0);
        }
        __syncthreads();
    }

#pragma unroll
    for (int nt = 0; nt < 8; ++nt) {
        const int R = row_base + nt * 16 + l16;
        const int b = R / N_;
        const int n = R - b * N_;
        __half* base = outp + ((size_t)(n * 8 + b)) * 128 + wave * 32 + quad * 4;
#pragma unroll
        for (int ft = 0; ft < 2; ++ft) {
            f32x4 a = acc[ft][nt];
            v4h h = {(_Float16)a.x, (_Float16)a.y, (_Float16)a.z, (_Float16)a.w};
            *(v4h*)(base + ft * 16) = h;
        }
    }
}

// ---------------------------------------------------------------- K2: edge scores (sorted, packed fp16)
__global__ __launch_bounds__(256) void k2_scores(const __half* __restrict__ ps,
                                                 const __half* __restrict__ pd,
                                                 const int* __restrict__ srcS,
                                                 const int* __restrict__ dstS,
                                                 const int* __restrict__ origS,
                                                 const __half* __restrict__ b1h,
                                                 const __half* __restrict__ w2h,
                                                 const float* __restrict__ b2,
                                                 const float* __restrict__ eattr,
                                                 float* __restrict__ scores) {
    const int tid = threadIdx.x;
    const int wave = tid >> 6;
    const int lane = tid & 63;
    // XCD swizzle: 40000 blocks, 5000 per XCD -> each XCD owns a contiguous
    // dst-slab of the dst-major-sorted edges (its 2.5 MB pd slab stays L2-hot).
    const int bid = blockIdx.x;
    const int lb = (bid & 7) * 5000 + (bid >> 3);
    const int e = lb * 4 + wave;

    const int b = lane >> 3;
    const int hi = (lane & 7) * 16;

    // per-lane constants in registers (no LDS, no bank conflicts)
    v2h b1p[8], w2p[8];
    {
        const v2h* bp = (const v2h*)(b1h + hi);
        const v2h* wp = (const v2h*)(w2h + hi);
#pragma unroll
        for (int j = 0; j < 8; j++) { b1p[j] = bp[j]; w2p[j] = wp[j]; }
    }

    const int src = srcS[e];
    const int dst = dstS[e];
    const int orig = origS[e];

    const float4* aps = (const float4*)&ps[((size_t)src * 8 + b) * 128 + hi];
    const float4* apd = (const float4*)&pd[((size_t)dst * 8 + b) * 128 + hi];
    float4 rs[2] = {aps[0], aps[1]};
    float4 rd[2] = {apd[0], apd[1]};
    const v2h* sv = (const v2h*)rs;
    const v2h* dv = (const v2h*)rd;

    const v2h slp = {(_Float16)SLOPE, (_Float16)SLOPE};
    float acc = 0.f;
#pragma unroll
    for (int j = 0; j < 8; j++) {
        v2h x = sv[j] + dv[j] + b1p[j];
        v2h l = __builtin_elementwise_max(x, x * slp);   // LeakyReLU, slope<1
        acc = dot2f(l, w2p[j], acc);
    }
    acc += __shfl_xor(acc, 1);
    acc += __shfl_xor(acc, 2);
    acc += __shfl_xor(acc, 4);

    if ((lane & 7) == 0) {
        scores[(size_t)b * E_ + orig] = (acc + b2[0]) * eattr[orig];
    }
}

// ---------------------------------------------------------------- K3a: partial max
__global__ __launch_bounds__(256) void k3a_max(const float* __restrict__ sc,
                                               float* __restrict__ pmax) {
    const int b = blockIdx.y, c = blockIdx.x, tid = threadIdx.x;
    const float* x = sc + (size_t)b * E_;
    const int i0 = c * (E_ / 32);
    float mv = -3.4e38f;
    for (int i = i0 + tid; i < i0 + E_ / 32; i += 256) mv = fmaxf(mv, x[i]);
    __shared__ float red[256];
    red[tid] = mv;
    __syncthreads();
    for (int s = 128; s > 0; s >>= 1) {
        if (tid < s) red[tid] = fmaxf(red[tid], red[tid + s]);
        __syncthreads();
    }
    if (tid == 0) pmax[b * 32 + c] = red[0];
}

// ---------------------------------------------------------------- K3b: final max
__global__ __launch_bounds__(256) void k3b_maxred(const float* __restrict__ pmax,
                                                  float* __restrict__ m) {
    const int t = threadIdx.x;
    float v = pmax[t];
#pragma unroll
    for (int k = 1; k <= 16; k <<= 1) v = fmaxf(v, __shfl_xor(v, k));
    if ((t & 31) == 0) m[t >> 5] = v;
}

// ---------------------------------------------------------------- K3c: partial exp-sums
__global__ __launch_bounds__(256) void k3c_sum(const float* __restrict__ sc,
                                               const float* __restrict__ m,
                                               double* __restrict__ psum) {
    const int b = blockIdx.y, c = blockIdx.x, tid = threadIdx.x;
    const float* x = sc + (size_t)b * E_;
    const float mv = m[b];
    const int i0 = c * (E_ / 32);
    double s = 0.0;
    for (int i = i0 + tid; i < i0 + E_ / 32; i += 256) s += (double)expf(x[i] - mv);
    __shared__ double red[256];
    red[tid] = s;
    __syncthreads();
    for (int st = 128; st > 0; st >>= 1) {
        if (tid < st) red[tid] += red[tid + st];
        __syncthreads();
    }
    if (tid == 0) psum[b * 32 + c] = red[0];
}

// ---------------------------------------------------------------- K3d: final sum -> inv
__global__ __launch_bounds__(256) void k3d_sumred(const double* __restrict__ psum,
                                                  float* __restrict__ inv) {
    const int t = threadIdx.x;
    double v = psum[t];
#pragma unroll
    for (int k = 1; k <= 16; k <<= 1) v += __shfl_xor(v, k);
    if ((t & 31) == 0) inv[t >> 5] = (float)(1.0 / v);
}

// ---------------------------------------------------------------- K3e: normalize w, write wT[e][8]
__global__ __launch_bounds__(256) void k3e_norm(float* __restrict__ sc,
                                                const float* __restrict__ m,
                                                const float* __restrict__ inv,
                                                float* __restrict__ wT) {
    const int e = blockIdx.x * 256 + threadIdx.x;
    float wv[8];
#pragma unroll
    for (int b = 0; b < 8; b++) {
        float v = expf(sc[(size_t)b * E_ + e] - m[b]) * inv[b];
        sc[(size_t)b * E_ + e] = v;  // in-place: scores buffer IS the w output
        wv[b] = v;
    }
    *(float4*)&wT[(size_t)e * 8]     = make_float4(wv[0], wv[1], wv[2], wv[3]);
    *(float4*)&wT[(size_t)e * 8 + 4] = make_float4(wv[4], wv[5], wv[6], wv[7]);
}

// ---------------------------------------------------------------- K3f: LDS-binned node-weight accumulation
__global__ __launch_bounds__(256) void k3f_bin(const int* __restrict__ ce,
                                               const float* __restrict__ wT,
                                               const unsigned char* __restrict__ cmT,
                                               float* __restrict__ Wpart) {
    const int ec = blockIdx.x;
    const int rg = blockIdx.y;
    const int n0 = rg * RANGE_;

    __shared__ float lWf[RANGE_ * 8];
    __shared__ float lWm[RANGE_ * 8];
    for (int i = threadIdx.x; i < RANGE_ * 8; i += 256) { lWf[i] = 0.f; lWm[i] = 0.f; }
    __syncthreads();

    const int4* dst4 = (const int4*)(ce + E_);
    const int base4 = ec * (E_ / EC_ / 4);
    for (int i = threadIdx.x; i < E_ / EC_ / 4; i += 256) {
        int4 d4 = dst4[base4 + i];
        int dd[4] = {d4.x, d4.y, d4.z, d4.w};
        const int e0 = (base4 + i) * 4;
#pragma unroll
        for (int j = 0; j < 4; ++j) {
            const int rel = dd[j] - n0;
            if ((unsigned)rel < (unsigned)RANGE_) {
                const int e = e0 + j;
                const int src = ce[e];
                float4 w0 = *(const float4*)&wT[(size_t)e * 8];
                float4 w1 = *(const float4*)&wT[(size_t)e * 8 + 4];
                const unsigned long long mm = *(const unsigned long long*)&cmT[src * 8];
                float wv[8] = {w0.x, w0.y, w0.z, w0.w, w1.x, w1.y, w1.z, w1.w};
                float* lf = &lWf[rel * 8];
                float* lm = &lWm[rel * 8];
#pragma unroll
                for (int b = 0; b < 8; b++) {
                    atomicAdd(&lf[b], wv[b]);
                    if ((mm >> (8 * b)) & 1ull) atomicAdd(&lm[b], wv[b]);
                }
            }
        }
    }
    __syncthreads();

    float* of = Wpart + ((size_t)ec * 2 + 0) * (NPAD_ * 8) + n0 * 8;
    float* om = Wpart + ((size_t)ec * 2 + 1) * (NPAD_ * 8) + n0 * 8;
    for (int i = threadIdx.x; i < RANGE_ * 8; i += 256) { of[i] = lWf[i]; om[i] = lWm[i]; }
}

// ---------------------------------------------------------------- K3g: reduce partials -> WfT/WmT [n][8]
__global__ __launch_bounds__(256) void k3g_reduce(const float* __restrict__ Wpart,
                                                  float* __restrict__ WfT,
                                                  float* __restrict__ WmT) {
    const int i = blockIdx.x * 256 + threadIdx.x;
    float sf = 0.f, sm = 0.f;
#pragma unroll
    for (int ec = 0; ec < EC_; ec++) {
        sf += Wpart[(size_t)ec * 2 * (NPAD_ * 8) + i];
        sm += Wpart[((size_t)ec * 2 + 1) * (NPAD_ * 8) + i];
    }
    WfT[i] = sf;
    WmT[i] = sm;
}

// ---------------------------------------------------------------- K4b: dense weighted sum over X
__global__ __launch_bounds__(256) void k4b_wsum(const float* __restrict__ X,
                                                const float* __restrict__ WmT,
                                                const float* __restrict__ WfT,
                                                float* __restrict__ gpart) {
    const int c = blockIdx.x;
    const int b = blockIdx.y;
    const int tx = threadIdx.x & 63;
    const int ty = threadIdx.x >> 6;
    const int npc = N_ / NCHUNK;
    const int n0 = c * npc;

    const float4* X4 = (const float4*)(X + (size_t)b * N_ * 256);
    float4 am = {0.f, 0.f, 0.f, 0.f};
    float4 af = {0.f, 0.f, 0.f, 0.f};

    for (int n = n0 + ty; n < n0 + npc; n += 4) {
        float wm = WmT[n * 8 + b];
        float wf = WfT[n * 8 + b];
        float4 v = X4[(size_t)n * 64 + tx];
        am.x = fmaf(wm, v.x, am.x); am.y = fmaf(wm, v.y, am.y);
        am.z = fmaf(wm, v.z, am.z); am.w = fmaf(wm, v.w, am.w);
        af.x = fmaf(wf, v.x, af.x); af.y = fmaf(wf, v.y, af.y);
        af.z = fmaf(wf, v.z, af.z); af.w = fmaf(wf, v.w, af.w);
    }

    __shared__ float4 red[256];
    red[threadIdx.x] = am;
    __syncthreads();
    if (ty == 0) {
        float4 r1 = red[tx + 64], r2 = red[tx + 128], r3 = red[tx + 192];
        am.x += r1.x + r2.x + r3.x; am.y += r1.y + r2.y + r3.y;
        am.z += r1.z + r2.z + r3.z; am.w += r1.w + r2.w + r3.w;
    }
    __syncthreads();
    red[threadIdx.x] = af;
    __syncthreads();
    if (ty == 0) {
        float4 r1 = red[tx + 64], r2 = red[tx + 128], r3 = red[tx + 192];
        af.x += r1.x + r2.x + r3.x; af.y += r1.y + r2.y + r3.y;
        af.z += r1.z + r2.z + r3.z; af.w += r1.w + r2.w + r3.w;
        float4* gp4 = (float4*)gpart;
        gp4[((c * 2 + 0) * 8 + b) * 64 + tx] = am;
        gp4[((c * 2 + 1) * 8 + b) * 64 + tx] = af;
    }
}

// ---------------------------------------------------------------- K5: finalize
__global__ __launch_bounds__(256) void k5_final(const float* __restrict__ gpart,
                                                const float* __restrict__ cnt,
                                                float* __restrict__ gf) {
    const int b = blockIdx.x;
    const int d = threadIdx.x;
    float sm = 0.f, sf = 0.f;
    for (int c = 0; c < NCHUNK; c++) {
        sm += gpart[((c * 2 + 0) * 8 + b) * 256 + d];
        sf += gpart[((c * 2 + 1) * 8 + b) * 256 + d];
    }
    const float cn = cnt[b];
    gf[b * 256 + d] = (cn > 0.f) ? (sm / cn) : (sf / (float)N_);
}

// ---------------------------------------------------------------- launch
extern "C" void kernel_launch(void* const* d_in, const int* in_sizes, int n_in,
                              void* d_out, int out_size, void* d_ws, size_t ws_size,
                              hipStream_t stream) {
    const float* X     = (const float*)d_in[0];
    const float* eattr = (const float*)d_in[1];
    const float* W1    = (const float*)d_in[2];
    const float* b1    = (const float*)d_in[3];
    const float* W2    = (const float*)d_in[4];
    const float* b2    = (const float*)d_in[5];
    const int*   eidx_raw = (const int*)d_in[6];
    const unsigned char* mask8 = (const unsigned char*)d_in[7];
    const unsigned int*  mask32 = (const unsigned int*)d_in[7];

    float* out  = (float*)d_out;
    float* gf   = out;          // [B,D]
    float* wout = out + 2048;   // [B,E]: scores -> softmaxed w in place

    // persistent region
    __half* ps_h = (__half*)d_ws;                         // [N*8*128] fp16 (20.48 MB)
    __half* pd_h = ps_h + (size_t)N_ * 8 * 128;           // [N*8*128] fp16
    __half* Wt   = pd_h + (size_t)N_ * 8 * 128;           // [2*128*256] fp16
    int* ce = (int*)(Wt + 2 * 128 * 256);                 // [2E]
    unsigned char* cmT = (unsigned char*)(ce + 2 * E_);   // [NPAD_*8]
    unsigned char* cm  = cmT + NPAD_ * 8;                 // [B*N]
    float* cnt = (float*)(cm + B_ * N_);                  // [8]
    int* flags = (int*)(cnt + 8);                         // [2]
    float* pmax = (float*)(flags + 2);                    // [256]
    float* mbuf = pmax + 256;                             // [8]
    float* invb = mbuf + 8;                               // [8]
    double* psum = (double*)(((uintptr_t)(invb + 8) + 15) & ~(uintptr_t)15);  // [256]
    float* gpart = (float*)(psum + 256);                  // [NCHUNK*2*8*256]
    int* hpart   = (int*)(gpart + NCHUNK * 2 * 8 * 256);  // [NB_*BINS_]
    int* offsetG = hpart + NB_ * BINS_;                   // [NB_*BINS_]
    int* srcS    = offsetG + NB_ * BINS_;                 // [E]
    int* dstS    = srcS + E_;                             // [E]
    int* origS   = dstS + E_;                             // [E]
    __half* b1h  = (__half*)(origS + E_);                 // [128]
    __half* w2h  = b1h + 128;                             // [128]

    // overlay region (reuses ps_h: dead after k2_scores) — 16.3 MB < 20.48 MB
    float* wT    = (float*)d_ws;                          // [E*8]
    float* Wpart = wT + (size_t)E_ * 8;                   // [EC_*2*NPAD_*8]
    float* WfT   = Wpart + (size_t)EC_ * 2 * NPAD_ * 8;   // [NPAD_*8]
    float* WmT   = WfT + NPAD_ * 8;                       // [NPAD_*8]

    hipLaunchKernelGGL(k_detect, dim3(1), dim3(64), 0, stream, eidx_raw, mask32, flags);
    hipLaunchKernelGGL(k_canon, dim3(1250), dim3(256), 0, stream,
                       eidx_raw, mask8, mask32, flags, ce, cm, cmT);
    hipLaunchKernelGGL(kW, dim3(256), dim3(256), 0, stream, W1, b1, W2, Wt, b1h, w2h);
    hipLaunchKernelGGL(k0_init, dim3(8), dim3(256), 0, stream, cm, cnt);
    hipLaunchKernelGGL(khist, dim3(NB_), dim3(256), 0, stream, ce, hpart);
    hipLaunchKernelGGL(kprefix, dim3(1), dim3(256), 0, stream, hpart, offsetG);
    hipLaunchKernelGGL(kscatter, dim3(NB_), dim3(256), 0, stream,
                       ce, offsetG, srcS, dstS, origS);
    hipLaunchKernelGGL(k1_mfma, dim3(625, 2), dim3(256), 0, stream, X, Wt, ps_h, pd_h);
    hipLaunchKernelGGL(k2_scores, dim3(E_ / 4), dim3(256), 0, stream,
                       ps_h, pd_h, srcS, dstS, origS, b1h, w2h, b2, eattr, wout);
    hipLaunchKernelGGL(k3a_max, dim3(32, 8), dim3(256), 0, stream, wout, pmax);
    hipLaunchKernelGGL(k3b_maxred, dim3(1), dim3(256), 0, stream, pmax, mbuf);
    hipLaunchKernelGGL(k3c_sum, dim3(32, 8), dim3(256), 0, stream, wout, mbuf, psum);
    hipLaunchKernelGGL(k3d_sumred, dim3(1), dim3(256), 0, stream, psum, invb);
    hipLaunchKernelGGL(k3e_norm, dim3(E_ / 256), dim3(256), 0, stream,
                       wout, mbuf, invb, wT);
    hipLaunchKernelGGL(k3f_bin, dim3(EC_, NR_), dim3(256), 0, stream, ce, wT, cmT, Wpart);
    hipLaunchKernelGGL(k3g_reduce, dim3(NPAD_ * 8 / 256), dim3(256), 0, stream,
                       Wpart, WfT, WmT);
    hipLaunchKernelGGL(k4b_wsum, dim3(NCHUNK, 8), dim3(256), 0, stream, X, WmT, WfT, gpart);
    hipLaunchKernelGGL(k5_final, dim3(8), dim3(256), 0, stream, gpart, cnt, gf);
}

// Round 7
// 314.595 us; speedup vs baseline: 2.1764x; 1.0314x over previous
//
#include <hip/hip_runtime.h>
#include <hip/hip_bf16.h>
#include <hip/hip_fp16.h>

#define B_ 8
#define N_ 10000
#define E_ 160000
#define D_ 256
#define H_ 128
#define SLOPE 0.2f
#define NCHUNK 50   // node chunks for dense weighted sum (200 nodes/chunk)

// binning config (node-weight accumulation)
#define EC_ 16            // edge chunks
#define NR_ 32            // node ranges
#define RANGE_ 320        // nodes per range
#define NPAD_ (NR_ * RANGE_)   // 10240 padded nodes

// edge-sort config (k2 locality)
#define NB_ 64            // histogram/scatter blocks
#define EPB_ (E_ / NB_)   // 2500 edges per block
#define BINS_ 256         // 16 dst-buckets x 16 src-buckets
#define NPB_ (N_ / 16)    // 625 nodes per bucket

// softmax stats config
#define SB_ 64            // stat blocks
#define SEB_ (E_ / SB_)   // 2500 edges per stat block

typedef __attribute__((ext_vector_type(8))) _Float16 v8h;
typedef __attribute__((ext_vector_type(4))) _Float16 v4h;
typedef __attribute__((ext_vector_type(2))) _Float16 v2h;
typedef __attribute__((ext_vector_type(4))) float f32x4;

static __device__ __forceinline__ float dot2f(v2h a, v2h b, float c) {
#if __has_builtin(__builtin_amdgcn_fdot2)
    return __builtin_amdgcn_fdot2(a, b, c, false);
#else
    return fmaf((float)a.y, (float)b.y, fmaf((float)a.x, (float)b.x, c));
#endif
}

// ---------------------------------------------------------------- K-detect
__global__ __launch_bounds__(64) void k_detect(const int* __restrict__ eidx_raw,
                                               const unsigned int* __restrict__ mask32,
                                               int* __restrict__ flags) {
    const int t = threadIdx.x;
    unsigned long long oddnz = __ballot(eidx_raw[2 * t + 1] != 0);
    unsigned long long mgt1  = __ballot(mask32[t] > 1u);
    if (t == 0) {
        flags[0] = (oddnz == 0ull) ? 1 : 0;  // edge_index is int64
        flags[1] = (mgt1 != 0ull) ? 1 : 0;   // mask is 1-byte bool
    }
}

// ---------------------------------------------------------------- K-canon (+ kW merged)
__global__ __launch_bounds__(256) void k_canon(const int* __restrict__ eidx_raw,
                                               const unsigned char* __restrict__ mask8,
                                               const unsigned int* __restrict__ mask32,
                                               const int* __restrict__ flags,
                                               const float* __restrict__ W1,
                                               const float* __restrict__ b1,
                                               const float* __restrict__ W2,
                                               int* __restrict__ ce,
                                               unsigned char* __restrict__ cm,
                                               unsigned char* __restrict__ cmT,
                                               __half* __restrict__ Wt,
                                               __half* __restrict__ b1h,
                                               __half* __restrict__ w2h) {
    const int i = blockIdx.x * 256 + threadIdx.x;
    const int f_e = flags[0], f_m = flags[1];
    if (i < 2 * E_) ce[i] = f_e ? eidx_raw[2 * i] : eidx_raw[i];
    if (i < B_ * N_) {
        unsigned char v = f_m ? (unsigned char)(mask8[i] != 0)
                              : (unsigned char)(mask32[i] != 0u);
        cm[i] = v;
        const int b = i / N_;
        const int n = i - b * N_;
        cmT[n * 8 + b] = v;
    }
    if (i < 2 * 256 * 128) {  // W1 -> fp16 transposed
        const int f = i & 127;
        const int row = i >> 7;       // 0..511
        const int c = row >> 8, k = row & 255;
        Wt[((c * 128 + f) * 256) + k] = __float2half(W1[row * 128 + f]);
    }
    if (i < 128) {
        b1h[i] = __float2half(b1[i]);
        w2h[i] = __float2half(W2[i]);
    }
}

// ---------------------------------------------------------------- khist (+ k0 count merged)
__global__ __launch_bounds__(256) void khist(const int* __restrict__ ce,
                                             const unsigned char* __restrict__ cm,
                                             int* __restrict__ hpart,
                                             float* __restrict__ cnt) {
    const int tid = threadIdx.x;
    if (blockIdx.x < NB_) {
        __shared__ int h[BINS_];
        h[tid] = 0;
        __syncthreads();
        const int base = blockIdx.x * EPB_;
        for (int i = tid; i < EPB_; i += 256) {
            const int s = ce[base + i], d = ce[E_ + base + i];
            const int bin = (d / NPB_) * 16 + s / NPB_;
            atomicAdd(&h[bin], 1);
        }
        __syncthreads();
        hpart[blockIdx.x * BINS_ + tid] = h[tid];
    } else {
        const int b = blockIdx.x - NB_;
        int c = 0;
        for (int i = tid; i < N_; i += 256) c += cm[b * N_ + i] ? 1 : 0;
        __shared__ int red[256];
        red[tid] = c;
        __syncthreads();
        for (int s = 128; s > 0; s >>= 1) {
            if (tid < s) red[tid] += red[tid + s];
            __syncthreads();
        }
        if (tid == 0) cnt[b] = (float)red[0];
    }
}

// ---------------------------------------------------------------- edge sort: prefix
__global__ __launch_bounds__(256) void kprefix(const int* __restrict__ hpart,
                                               int* __restrict__ offsetG) {
    __shared__ int cnt[BINS_];
    __shared__ int excl[BINS_];
    const int bin = threadIdx.x;
    int c = 0;
    for (int b = 0; b < NB_; b++) c += hpart[b * BINS_ + bin];
    cnt[bin] = c;
    __syncthreads();
    if (bin == 0) {
        int r = 0;
        for (int i = 0; i < BINS_; i++) { excl[i] = r; r += cnt[i]; }
    }
    __syncthreads();
    int run = excl[bin];
    for (int b = 0; b < NB_; b++) {
        offsetG[b * BINS_ + bin] = run;
        run += hpart[b * BINS_ + bin];
    }
}

// ---------------------------------------------------------------- edge sort: scatter (+ rank)
__global__ __launch_bounds__(256) void kscatter(const int* __restrict__ ce,
                                                const int* __restrict__ offsetG,
                                                int* __restrict__ srcS,
                                                int* __restrict__ dstS,
                                                int* __restrict__ origS,
                                                int* __restrict__ rank) {
    __shared__ int loc[BINS_];
    const int tid = threadIdx.x;
    loc[tid] = offsetG[blockIdx.x * BINS_ + tid];
    __syncthreads();
    const int base = blockIdx.x * EPB_;
    for (int i = tid; i < EPB_; i += 256) {
        const int e = base + i;
        const int s = ce[e], d = ce[E_ + e];
        const int bin = (d / NPB_) * 16 + s / NPB_;
        const int pos = atomicAdd(&loc[bin], 1);
        srcS[pos] = s;
        dstS[pos] = d;
        origS[pos] = e;
        rank[e] = pos;
    }
}

// ---------------------------------------------------------------- K1: MFMA projection GEMM (both halves, one X pass)
__global__ __launch_bounds__(256) void k1_mfma(const float* __restrict__ X,
                                               const __half* __restrict__ Wt,
                                               __half* __restrict__ ps,
                                               __half* __restrict__ pd) {
    const int rb = blockIdx.x;   // 0..624
    const int tid = threadIdx.x;
    const int wave = tid >> 6, lane = tid & 63;
    const int quad = lane >> 4, l16 = lane & 15;

    __shared__ _Float16 Xs[128 * 40];

    f32x4 acc[2][2][8];  // [cb][ft][nt]
#pragma unroll
    for (int c = 0; c < 2; c++)
#pragma unroll
        for (int i = 0; i < 2; i++)
#pragma unroll
            for (int j = 0; j < 8; j++) acc[c][i][j] = (f32x4){0.f, 0.f, 0.f, 0.f};

    const int row_base = rb * 128;
    const int sr = tid >> 1;
    const int sh = tid & 1;

    for (int kc = 0; kc < 8; ++kc) {
        {
            const float4* src = (const float4*)&X[(size_t)(row_base + sr) * 256 + kc * 32 + sh * 16];
            _Float16* dst = &Xs[sr * 40 + sh * 16];
#pragma unroll
            for (int j = 0; j < 4; ++j) {
                float4 v = src[j];
                v4h p = {(_Float16)v.x, (_Float16)v.y, (_Float16)v.z, (_Float16)v.w};
                *(v4h*)&dst[j * 4] = p;
            }
        }
        __syncthreads();

        // W fragments straight from global (128 KB, L2-hot)
        v8h wf[2][2];
#pragma unroll
        for (int cb = 0; cb < 2; ++cb)
#pragma unroll
            for (int ft = 0; ft < 2; ++ft)
                wf[cb][ft] = *(const v8h*)&Wt[((size_t)cb * 128 + wave * 32 + ft * 16 + l16) * 256 + kc * 32 + quad * 8];

#pragma unroll
        for (int nt = 0; nt < 8; ++nt) {
            v8h xf = *(v8h*)&Xs[(nt * 16 + l16) * 40 + quad * 8];
            acc[0][0][nt] = __builtin_amdgcn_mfma_f32_16x16x32_f16(wf[0][0], xf, acc[0][0][nt], 0, 0, 0);
            acc[0][1][nt] = __builtin_amdgcn_mfma_f32_16x16x32_f16(wf[0][1], xf, acc[0][1][nt], 0, 0, 0);
            acc[1][0][nt] = __builtin_amdgcn_mfma_f32_16x16x32_f16(wf[1][0], xf, acc[1][0][nt], 0, 0, 0);
            acc[1][1][nt] = __builtin_amdgcn_mfma_f32_16x16x32_f16(wf[1][1], xf, acc[1][1][nt], 0, 0, 0);
        }
        __syncthreads();
    }

#pragma unroll
    for (int nt = 0; nt < 8; ++nt) {
        const int R = row_base + nt * 16 + l16;
        const int b = R / N_;
        const int n = R - b * N_;
        const size_t off = ((size_t)(n * 8 + b)) * 128 + wave * 32 + quad * 4;
#pragma unroll
        for (int cb = 0; cb < 2; ++cb) {
            __half* base = (cb ? pd : ps) + off;
#pragma unroll
            for (int ft = 0; ft < 2; ++ft) {
                f32x4 a = acc[cb][ft][nt];
                v4h h = {(_Float16)a.x, (_Float16)a.y, (_Float16)a.z, (_Float16)a.w};
                *(v4h*)(base + ft * 16) = h;
            }
        }
    }
}

// ---------------------------------------------------------------- K2: edge scores -> scS[pos][8] (coalesced)
__global__ __launch_bounds__(256) void k2_scores(const __half* __restrict__ ps,
                                                 const __half* __restrict__ pd,
                                                 const int* __restrict__ srcS,
                                                 const int* __restrict__ dstS,
                                                 const int* __restrict__ origS,
                                                 const __half* __restrict__ b1h,
                                                 const __half* __restrict__ w2h,
                                                 const float* __restrict__ b2,
                                                 const float* __restrict__ eattr,
                                                 float* __restrict__ scS) {
    const int tid = threadIdx.x;
    const int wave = tid >> 6;
    const int lane = tid & 63;
    const int bid = blockIdx.x;
    const int lb = (bid & 7) * 5000 + (bid >> 3);  // XCD swizzle
    const int e = lb * 4 + wave;

    const int b = lane >> 3;
    const int hi = (lane & 7) * 16;

    v2h b1p[8], w2p[8];
    {
        const v2h* bp = (const v2h*)(b1h + hi);
        const v2h* wp = (const v2h*)(w2h + hi);
#pragma unroll
        for (int j = 0; j < 8; j++) { b1p[j] = bp[j]; w2p[j] = wp[j]; }
    }

    const int src = srcS[e];
    const int dst = dstS[e];
    const int orig = origS[e];

    const float4* aps = (const float4*)&ps[((size_t)src * 8 + b) * 128 + hi];
    const float4* apd = (const float4*)&pd[((size_t)dst * 8 + b) * 128 + hi];
    float4 rs[2] = {aps[0], aps[1]};
    float4 rd[2] = {apd[0], apd[1]};
    const v2h* sv = (const v2h*)rs;
    const v2h* dv = (const v2h*)rd;

    const v2h slp = {(_Float16)SLOPE, (_Float16)SLOPE};
    float acc = 0.f;
#pragma unroll
    for (int j = 0; j < 8; j++) {
        v2h x = sv[j] + dv[j] + b1p[j];
        v2h l = __builtin_elementwise_max(x, x * slp);   // LeakyReLU, slope<1
        acc = dot2f(l, w2p[j], acc);
    }
    acc += __shfl_xor(acc, 1);
    acc += __shfl_xor(acc, 2);
    acc += __shfl_xor(acc, 4);

    if ((lane & 7) == 0) {
        scS[(size_t)e * 8 + b] = (acc + b2[0]) * eattr[orig];
    }
}

// ---------------------------------------------------------------- K3a: per-chunk per-batch max (edge-major)
__global__ __launch_bounds__(256) void k3a_max(const float* __restrict__ scS,
                                               float* __restrict__ pmax) {
    const int tid = threadIdx.x;
    const int wave = tid >> 6, lane = tid & 63;
    const int base = blockIdx.x * SEB_;
    float fm[8];
#pragma unroll
    for (int j = 0; j < 8; j++) fm[j] = -3.4e38f;
    for (int i = tid; i < SEB_; i += 256) {
        const float4* s4 = (const float4*)&scS[(size_t)(base + i) * 8];
        float4 a = s4[0], b = s4[1];
        fm[0] = fmaxf(fm[0], a.x); fm[1] = fmaxf(fm[1], a.y);
        fm[2] = fmaxf(fm[2], a.z); fm[3] = fmaxf(fm[3], a.w);
        fm[4] = fmaxf(fm[4], b.x); fm[5] = fmaxf(fm[5], b.y);
        fm[6] = fmaxf(fm[6], b.z); fm[7] = fmaxf(fm[7], b.w);
    }
#pragma unroll
    for (int k = 1; k <= 32; k <<= 1)
#pragma unroll
        for (int j = 0; j < 8; j++) fm[j] = fmaxf(fm[j], __shfl_xor(fm[j], k));
    __shared__ float lmax[4][8];
    if (lane == 0)
#pragma unroll
        for (int j = 0; j < 8; j++) lmax[wave][j] = fm[j];
    __syncthreads();
    if (tid < 8) {
        float v = fmaxf(fmaxf(lmax[0][tid], lmax[1][tid]), fmaxf(lmax[2][tid], lmax[3][tid]));
        pmax[blockIdx.x * 8 + tid] = v;
    }
}

// ---------------------------------------------------------------- K3c: per-chunk per-batch exp-sums (m reduced inline)
__global__ __launch_bounds__(256) void k3c_sum(const float* __restrict__ scS,
                                               const float* __restrict__ pmax,
                                               double* __restrict__ psum) {
    const int tid = threadIdx.x;
    const int wave = tid >> 6, lane = tid & 63;
    __shared__ float sm[8];
    if (tid < SB_) {
        float v[8];
        const float4* p4 = (const float4*)&pmax[tid * 8];
        float4 a = p4[0], b = p4[1];
        v[0] = a.x; v[1] = a.y; v[2] = a.z; v[3] = a.w;
        v[4] = b.x; v[5] = b.y; v[6] = b.z; v[7] = b.w;
#pragma unroll
        for (int k = 1; k <= 32; k <<= 1)
#pragma unroll
            for (int j = 0; j < 8; j++) v[j] = fmaxf(v[j], __shfl_xor(v[j], k));
        if (tid == 0)
#pragma unroll
            for (int j = 0; j < 8; j++) sm[j] = v[j];
    }
    __syncthreads();
    float m[8];
#pragma unroll
    for (int j = 0; j < 8; j++) m[j] = sm[j];

    const int base = blockIdx.x * SEB_;
    double s[8];
#pragma unroll
    for (int j = 0; j < 8; j++) s[j] = 0.0;
    for (int i = tid; i < SEB_; i += 256) {
        const float4* s4 = (const float4*)&scS[(size_t)(base + i) * 8];
        float4 a = s4[0], b = s4[1];
        s[0] += (double)expf(a.x - m[0]); s[1] += (double)expf(a.y - m[1]);
        s[2] += (double)expf(a.z - m[2]); s[3] += (double)expf(a.w - m[3]);
        s[4] += (double)expf(b.x - m[4]); s[5] += (double)expf(b.y - m[5]);
        s[6] += (double)expf(b.z - m[6]); s[7] += (double)expf(b.w - m[7]);
    }
#pragma unroll
    for (int k = 1; k <= 32; k <<= 1)
#pragma unroll
        for (int j = 0; j < 8; j++) s[j] += __shfl_xor(s[j], k);
    __shared__ double lsum[4][8];
    if (lane == 0)
#pragma unroll
        for (int j = 0; j < 8; j++) lsum[wave][j] = s[j];
    __syncthreads();
    if (tid < 8) {
        psum[blockIdx.x * 8 + tid] = lsum[0][tid] + lsum[1][tid] + lsum[2][tid] + lsum[3][tid];
    }
}

// ---------------------------------------------------------------- K3e: normalize (stats inline) -> wout coalesced + wT
__global__ __launch_bounds__(256) void k3e_norm(const float* __restrict__ scS,
                                                const int* __restrict__ rank,
                                                const float* __restrict__ pmax,
                                                const double* __restrict__ psum,
                                                float* __restrict__ wout,
                                                float* __restrict__ wT) {
    const int tid = threadIdx.x;
    __shared__ float smx[8], sinvx[8];
    if (tid < 64) {               // wave 0: global max
        float v[8];
        const float4* p4 = (const float4*)&pmax[tid * 8];
        float4 a = p4[0], b = p4[1];
        v[0] = a.x; v[1] = a.y; v[2] = a.z; v[3] = a.w;
        v[4] = b.x; v[5] = b.y; v[6] = b.z; v[7] = b.w;
#pragma unroll
        for (int k = 1; k <= 32; k <<= 1)
#pragma unroll
            for (int j = 0; j < 8; j++) v[j] = fmaxf(v[j], __shfl_xor(v[j], k));
        if (tid == 0)
#pragma unroll
            for (int j = 0; j < 8; j++) smx[j] = v[j];
    } else if (tid < 128) {       // wave 1: global sum -> inv
        const int l = tid - 64;
        double s[8];
#pragma unroll
        for (int j = 0; j < 8; j++) s[j] = psum[l * 8 + j];
#pragma unroll
        for (int k = 1; k <= 32; k <<= 1)
#pragma unroll
            for (int j = 0; j < 8; j++) s[j] += __shfl_xor(s[j], k);
        if (l == 0)
#pragma unroll
            for (int j = 0; j < 8; j++) sinvx[j] = (float)(1.0 / s[j]);
    }
    __syncthreads();

    const int e = blockIdx.x * 256 + tid;
    const int p = rank[e];
    const float4* s4 = (const float4*)&scS[(size_t)p * 8];
    float4 a = s4[0], b = s4[1];
    float wv[8];
    wv[0] = expf(a.x - smx[0]) * sinvx[0]; wv[1] = expf(a.y - smx[1]) * sinvx[1];
    wv[2] = expf(a.z - smx[2]) * sinvx[2]; wv[3] = expf(a.w - smx[3]) * sinvx[3];
    wv[4] = expf(b.x - smx[4]) * sinvx[4]; wv[5] = expf(b.y - smx[5]) * sinvx[5];
    wv[6] = expf(b.z - smx[6]) * sinvx[6]; wv[7] = expf(b.w - smx[7]) * sinvx[7];
#pragma unroll
    for (int j = 0; j < 8; j++) wout[(size_t)j * E_ + e] = wv[j];   // coalesced
    *(float4*)&wT[(size_t)e * 8]     = make_float4(wv[0], wv[1], wv[2], wv[3]);
    *(float4*)&wT[(size_t)e * 8 + 4] = make_float4(wv[4], wv[5], wv[6], wv[7]);
}

// ---------------------------------------------------------------- K3f: LDS-binned node-weight accumulation
__global__ __launch_bounds__(256) void k3f_bin(const int* __restrict__ ce,
                                               const float* __restrict__ wT,
                                               const unsigned char* __restrict__ cmT,
                                               float* __restrict__ Wpart) {
    const int ec = blockIdx.x;
    const int rg = blockIdx.y;
    const int n0 = rg * RANGE_;

    __shared__ float lWf[RANGE_ * 8];
    __shared__ float lWm[RANGE_ * 8];
    for (int i = threadIdx.x; i < RANGE_ * 8; i += 256) { lWf[i] = 0.f; lWm[i] = 0.f; }
    __syncthreads();

    const int4* dst4 = (const int4*)(ce + E_);
    const int base4 = ec * (E_ / EC_ / 4);
    for (int i = threadIdx.x; i < E_ / EC_ / 4; i += 256) {
        int4 d4 = dst4[base4 + i];
        int dd[4] = {d4.x, d4.y, d4.z, d4.w};
        const int e0 = (base4 + i) * 4;
#pragma unroll
        for (int j = 0; j < 4; ++j) {
            const int rel = dd[j] - n0;
            if ((unsigned)rel < (unsigned)RANGE_) {
                const int e = e0 + j;
                const int src = ce[e];
                float4 w0 = *(const float4*)&wT[(size_t)e * 8];
                float4 w1 = *(const float4*)&wT[(size_t)e * 8 + 4];
                const unsigned long long mm = *(const unsigned long long*)&cmT[src * 8];
                float wv[8] = {w0.x, w0.y, w0.z, w0.w, w1.x, w1.y, w1.z, w1.w};
                float* lf = &lWf[rel * 8];
                float* lm = &lWm[rel * 8];
#pragma unroll
                for (int b = 0; b < 8; b++) {
                    atomicAdd(&lf[b], wv[b]);
                    if ((mm >> (8 * b)) & 1ull) atomicAdd(&lm[b], wv[b]);
                }
            }
        }
    }
    __syncthreads();

    float* of = Wpart + ((size_t)ec * 2 + 0) * (NPAD_ * 8) + n0 * 8;
    float* om = Wpart + ((size_t)ec * 2 + 1) * (NPAD_ * 8) + n0 * 8;
    for (int i = threadIdx.x; i < RANGE_ * 8; i += 256) { of[i] = lWf[i]; om[i] = lWm[i]; }
}

// ---------------------------------------------------------------- K3g: reduce partials -> WfT/WmT [n][8]
__global__ __launch_bounds__(256) void k3g_reduce(const float* __restrict__ Wpart,
                                                  float* __restrict__ WfT,
                                                  float* __restrict__ WmT) {
    const int i = blockIdx.x * 256 + threadIdx.x;
    float sf = 0.f, sm = 0.f;
#pragma unroll
    for (int ec = 0; ec < EC_; ec++) {
        sf += Wpart[(size_t)ec * 2 * (NPAD_ * 8) + i];
        sm += Wpart[((size_t)ec * 2 + 1) * (NPAD_ * 8) + i];
    }
    WfT[i] = sf;
    WmT[i] = sm;
}

// ---------------------------------------------------------------- K4b: dense weighted sum over X
__global__ __launch_bounds__(256) void k4b_wsum(const float* __restrict__ X,
                                                const float* __restrict__ WmT,
                                                const float* __restrict__ WfT,
                                                float* __restrict__ gpart) {
    const int c = blockIdx.x;
    const int b = blockIdx.y;
    const int tx = threadIdx.x & 63;
    const int ty = threadIdx.x >> 6;
    const int npc = N_ / NCHUNK;
    const int n0 = c * npc;

    const float4* X4 = (const float4*)(X + (size_t)b * N_ * 256);
    float4 am = {0.f, 0.f, 0.f, 0.f};
    float4 af = {0.f, 0.f, 0.f, 0.f};

    for (int n = n0 + ty; n < n0 + npc; n += 4) {
        float wm = WmT[n * 8 + b];
        float wf = WfT[n * 8 + b];
        float4 v = X4[(size_t)n * 64 + tx];
        am.x = fmaf(wm, v.x, am.x); am.y = fmaf(wm, v.y, am.y);
        am.z = fmaf(wm, v.z, am.z); am.w = fmaf(wm, v.w, am.w);
        af.x = fmaf(wf, v.x, af.x); af.y = fmaf(wf, v.y, af.y);
        af.z = fmaf(wf, v.z, af.z); af.w = fmaf(wf, v.w, af.w);
    }

    __shared__ float4 red[256];
    red[threadIdx.x] = am;
    __syncthreads();
    if (ty == 0) {
        float4 r1 = red[tx + 64], r2 = red[tx + 128], r3 = red[tx + 192];
        am.x += r1.x + r2.x + r3.x; am.y += r1.y + r2.y + r3.y;
        am.z += r1.z + r2.z + r3.z; am.w += r1.w + r2.w + r3.w;
    }
    __syncthreads();
    red[threadIdx.x] = af;
    __syncthreads();
    if (ty == 0) {
        float4 r1 = red[tx + 64], r2 = red[tx + 128], r3 = red[tx + 192];
        af.x += r1.x + r2.x + r3.x; af.y += r1.y + r2.y + r3.y;
        af.z += r1.z + r2.z + r3.z; af.w += r1.w + r2.w + r3.w;
        float4* gp4 = (float4*)gpart;
        gp4[((c * 2 + 0) * 8 + b) * 64 + tx] = am;
        gp4[((c * 2 + 1) * 8 + b) * 64 + tx] = af;
    }
}

// ---------------------------------------------------------------- K5: finalize
__global__ __launch_bounds__(256) void k5_final(const float* __restrict__ gpart,
                                                const float* __restrict__ cnt,
                                                float* __restrict__ gf) {
    const int b = blockIdx.x;
    const int d = threadIdx.x;
    float sm = 0.f, sf = 0.f;
    for (int c = 0; c < NCHUNK; c++) {
        sm += gpart[((c * 2 + 0) * 8 + b) * 256 + d];
        sf += gpart[((c * 2 + 1) * 8 + b) * 256 + d];
    }
    const float cn = cnt[b];
    gf[b * 256 + d] = (cn > 0.f) ? (sm / cn) : (sf / (float)N_);
}

// ---------------------------------------------------------------- launch
extern "C" void kernel_launch(void* const* d_in, const int* in_sizes, int n_in,
                              void* d_out, int out_size, void* d_ws, size_t ws_size,
                              hipStream_t stream) {
    const float* X     = (const float*)d_in[0];
    const float* eattr = (const float*)d_in[1];
    const float* W1    = (const float*)d_in[2];
    const float* b1    = (const float*)d_in[3];
    const float* W2    = (const float*)d_in[4];
    const float* b2    = (const float*)d_in[5];
    const int*   eidx_raw = (const int*)d_in[6];
    const unsigned char* mask8 = (const unsigned char*)d_in[7];
    const unsigned int*  mask32 = (const unsigned int*)d_in[7];

    float* out  = (float*)d_out;
    float* gf   = out;          // [B,D]
    float* wout = out + 2048;   // [B,E]

    // persistent region
    __half* ps_h = (__half*)d_ws;                         // [N*8*128] fp16 (20.48 MB)
    __half* pd_h = ps_h + (size_t)N_ * 8 * 128;           // [N*8*128] fp16
    __half* Wt   = pd_h + (size_t)N_ * 8 * 128;           // [2*128*256] fp16
    int* ce = (int*)(Wt + 2 * 128 * 256);                 // [2E]
    unsigned char* cmT = (unsigned char*)(ce + 2 * E_);   // [NPAD_*8]
    unsigned char* cm  = cmT + NPAD_ * 8;                 // [B*N]
    float* cnt = (float*)(cm + B_ * N_);                  // [8]
    int* flags = (int*)(cnt + 8);                         // [2]
    float* pmax = (float*)(flags + 2);                    // [SB_*8]
    double* psum = (double*)(((uintptr_t)(pmax + SB_ * 8) + 15) & ~(uintptr_t)15);  // [SB_*8]
    float* gpart = (float*)(psum + SB_ * 8);              // [NCHUNK*2*8*256]
    int* hpart   = (int*)(gpart + NCHUNK * 2 * 8 * 256);  // [NB_*BINS_]
    int* offsetG = hpart + NB_ * BINS_;                   // [NB_*BINS_]
    int* srcS    = offsetG + NB_ * BINS_;                 // [E]
    int* dstS    = srcS + E_;                             // [E]
    int* origS   = dstS + E_;                             // [E]
    int* rankB   = origS + E_;                            // [E]
    __half* b1h  = (__half*)(rankB + E_);                 // [128]
    __half* w2h  = b1h + 128;                             // [128]
    float* scS   = (float*)(w2h + 128);                   // [E*8] sorted edge-major scores

    // overlay region (reuses ps_h: dead after k2_scores) — 16.3 MB < 20.48 MB
    float* wT    = (float*)d_ws;                          // [E*8]
    float* Wpart = wT + (size_t)E_ * 8;                   // [EC_*2*NPAD_*8]
    float* WfT   = Wpart + (size_t)EC_ * 2 * NPAD_ * 8;   // [NPAD_*8]
    float* WmT   = WfT + NPAD_ * 8;                       // [NPAD_*8]

    hipLaunchKernelGGL(k_detect, dim3(1), dim3(64), 0, stream, eidx_raw, mask32, flags);
    hipLaunchKernelGGL(k_canon, dim3(1250), dim3(256), 0, stream,
                       eidx_raw, mask8, mask32, flags, W1, b1, W2,
                       ce, cm, cmT, Wt, b1h, w2h);
    hipLaunchKernelGGL(khist, dim3(NB_ + 8), dim3(256), 0, stream, ce, cm, hpart, cnt);
    hipLaunchKernelGGL(kprefix, dim3(1), dim3(256), 0, stream, hpart, offsetG);
    hipLaunchKernelGGL(kscatter, dim3(NB_), dim3(256), 0, stream,
                       ce, offsetG, srcS, dstS, origS, rankB);
    hipLaunchKernelGGL(k1_mfma, dim3(625), dim3(256), 0, stream, X, Wt, ps_h, pd_h);
    hipLaunchKernelGGL(k2_scores, dim3(E_ / 4), dim3(256), 0, stream,
                       ps_h, pd_h, srcS, dstS, origS, b1h, w2h, b2, eattr, scS);
    hipLaunchKernelGGL(k3a_max, dim3(SB_), dim3(256), 0, stream, scS, pmax);
    hipLaunchKernelGGL(k3c_sum, dim3(SB_), dim3(256), 0, stream, scS, pmax, psum);
    hipLaunchKernelGGL(k3e_norm, dim3(E_ / 256), dim3(256), 0, stream,
                       scS, rankB, pmax, psum, wout, wT);
    hipLaunchKernelGGL(k3f_bin, dim3(EC_, NR_), dim3(256), 0, stream, ce, wT, cmT, Wpart);
    hipLaunchKernelGGL(k3g_reduce, dim3(NPAD_ * 8 / 256), dim3(256), 0, stream,
                       Wpart, WfT, WmT);
    hipLaunchKernelGGL(k4b_wsum, dim3(NCHUNK, 8), dim3(256), 0, stream, X, WmT, WfT, gpart);
    hipLaunchKernelGGL(k5_final, dim3(8), dim3(256), 0, stream, gpart, cnt, gf);
}

// Round 8
// 299.162 us; speedup vs baseline: 2.2887x; 1.0516x over previous
//
#include <hip/hip_runtime.h>
#include <hip/hip_bf16.h>
#include <hip/hip_fp16.h>

#define B_ 8
#define N_ 10000
#define E_ 160000
#define D_ 256
#define H_ 128
#define SLOPE 0.2f
#define NCHUNK 50   // node chunks for dense weighted sum (200 nodes/chunk)

// edge-sort config
#define NB_ 64            // histogram/scatter blocks
#define EPB_ (E_ / NB_)   // 2500 edges per block
#define BINS_ 256         // 16 dst-buckets x 16 src-buckets
#define NPB_ (N_ / 16)    // 625 nodes per bucket

// softmax stats config
#define SB_ 64            // stat blocks
#define SEB_ (E_ / SB_)   // 2500 edges per stat block

typedef __attribute__((ext_vector_type(8))) _Float16 v8h;
typedef __attribute__((ext_vector_type(4))) _Float16 v4h;
typedef __attribute__((ext_vector_type(2))) _Float16 v2h;
typedef __attribute__((ext_vector_type(4))) float f32x4;

static __device__ __forceinline__ float dot2f(v2h a, v2h b, float c) {
#if __has_builtin(__builtin_amdgcn_fdot2)
    return __builtin_amdgcn_fdot2(a, b, c, false);
#else
    return fmaf((float)a.y, (float)b.y, fmaf((float)a.x, (float)b.x, c));
#endif
}

// ---------------------------------------------------------------- K-detect
__global__ __launch_bounds__(64) void k_detect(const int* __restrict__ eidx_raw,
                                               const unsigned int* __restrict__ mask32,
                                               int* __restrict__ flags) {
    const int t = threadIdx.x;
    unsigned long long oddnz = __ballot(eidx_raw[2 * t + 1] != 0);
    unsigned long long mgt1  = __ballot(mask32[t] > 1u);
    if (t == 0) {
        flags[0] = (oddnz == 0ull) ? 1 : 0;  // edge_index is int64
        flags[1] = (mgt1 != 0ull) ? 1 : 0;   // mask is 1-byte bool
    }
}

// ---------------------------------------------------------------- K-canon (+ kW merged)
__global__ __launch_bounds__(256) void k_canon(const int* __restrict__ eidx_raw,
                                               const unsigned char* __restrict__ mask8,
                                               const unsigned int* __restrict__ mask32,
                                               const int* __restrict__ flags,
                                               const float* __restrict__ W1,
                                               const float* __restrict__ b1,
                                               const float* __restrict__ W2,
                                               int* __restrict__ ce,
                                               unsigned char* __restrict__ cm,
                                               unsigned char* __restrict__ cmT,
                                               __half* __restrict__ Wt,
                                               __half* __restrict__ b1h,
                                               __half* __restrict__ w2h) {
    const int i = blockIdx.x * 256 + threadIdx.x;
    const int f_e = flags[0], f_m = flags[1];
    if (i < 2 * E_) ce[i] = f_e ? eidx_raw[2 * i] : eidx_raw[i];
    if (i < B_ * N_) {
        unsigned char v = f_m ? (unsigned char)(mask8[i] != 0)
                              : (unsigned char)(mask32[i] != 0u);
        cm[i] = v;
        const int b = i / N_;
        const int n = i - b * N_;
        cmT[n * 8 + b] = v;
    }
    if (i < 2 * 256 * 128) {  // W1 -> fp16 transposed
        const int f = i & 127;
        const int row = i >> 7;       // 0..511
        const int c = row >> 8, k = row & 255;
        Wt[((c * 128 + f) * 256) + k] = __float2half(W1[row * 128 + f]);
    }
    if (i < 128) {
        b1h[i] = __float2half(b1[i]);
        w2h[i] = __float2half(W2[i]);
    }
}

// ---------------------------------------------------------------- khist (+ mask count merged)
__global__ __launch_bounds__(256) void khist(const int* __restrict__ ce,
                                             const unsigned char* __restrict__ cm,
                                             int* __restrict__ hpart,
                                             float* __restrict__ cnt) {
    const int tid = threadIdx.x;
    if (blockIdx.x < NB_) {
        __shared__ int h[BINS_];
        h[tid] = 0;
        __syncthreads();
        const int base = blockIdx.x * EPB_;
        for (int i = tid; i < EPB_; i += 256) {
            const int s = ce[base + i], d = ce[E_ + base + i];
            const int bin = (d / NPB_) * 16 + s / NPB_;
            atomicAdd(&h[bin], 1);
        }
        __syncthreads();
        hpart[blockIdx.x * BINS_ + tid] = h[tid];
    } else {
        const int b = blockIdx.x - NB_;
        int c = 0;
        for (int i = tid; i < N_; i += 256) c += cm[b * N_ + i] ? 1 : 0;
        __shared__ int red[256];
        red[tid] = c;
        __syncthreads();
        for (int s = 128; s > 0; s >>= 1) {
            if (tid < s) red[tid] += red[tid + s];
            __syncthreads();
        }
        if (tid == 0) cnt[b] = (float)red[0];
    }
}

// ---------------------------------------------------------------- edge sort: prefix (+ bucket starts)
__global__ __launch_bounds__(256) void kprefix(const int* __restrict__ hpart,
                                               int* __restrict__ offsetG,
                                               int* __restrict__ bstart) {
    __shared__ int cnt[BINS_];
    __shared__ int excl[BINS_];
    const int bin = threadIdx.x;
    int c = 0;
    for (int b = 0; b < NB_; b++) c += hpart[b * BINS_ + bin];
    cnt[bin] = c;
    __syncthreads();
    if (bin == 0) {
        int r = 0;
        for (int i = 0; i < BINS_; i++) { excl[i] = r; r += cnt[i]; }
    }
    __syncthreads();
    if ((bin & 15) == 0) bstart[bin >> 4] = excl[bin];
    if (bin == 0) bstart[16] = E_;
    int run = excl[bin];
    for (int b = 0; b < NB_; b++) {
        offsetG[b * BINS_ + bin] = run;
        run += hpart[b * BINS_ + bin];
    }
}

// ---------------------------------------------------------------- edge sort: scatter (packed records + rank)
__global__ __launch_bounds__(256) void kscatter(const int* __restrict__ ce,
                                                const int* __restrict__ offsetG,
                                                int4* __restrict__ esort,
                                                int* __restrict__ rank) {
    __shared__ int loc[BINS_];
    const int tid = threadIdx.x;
    loc[tid] = offsetG[blockIdx.x * BINS_ + tid];
    __syncthreads();
    const int base = blockIdx.x * EPB_;
    for (int i = tid; i < EPB_; i += 256) {
        const int e = base + i;
        const int s = ce[e], d = ce[E_ + e];
        const int bin = (d / NPB_) * 16 + s / NPB_;
        const int pos = atomicAdd(&loc[bin], 1);
        esort[pos] = make_int4(s, d, e, 0);
        rank[e] = pos;
    }
}

// ---------------------------------------------------------------- K1: MFMA projection GEMM (both halves, one X pass)
__global__ __launch_bounds__(256) void k1_mfma(const float* __restrict__ X,
                                               const __half* __restrict__ Wt,
                                               __half* __restrict__ ps,
                                               __half* __restrict__ pd) {
    const int rb = blockIdx.x;   // 0..624
    const int tid = threadIdx.x;
    const int wave = tid >> 6, lane = tid & 63;
    const int quad = lane >> 4, l16 = lane & 15;

    __shared__ _Float16 Xs[128 * 40];

    f32x4 acc[2][2][8];  // [cb][ft][nt]
#pragma unroll
    for (int c = 0; c < 2; c++)
#pragma unroll
        for (int i = 0; i < 2; i++)
#pragma unroll
            for (int j = 0; j < 8; j++) acc[c][i][j] = (f32x4){0.f, 0.f, 0.f, 0.f};

    const int row_base = rb * 128;
    const int sr = tid >> 1;
    const int sh = tid & 1;

    for (int kc = 0; kc < 8; ++kc) {
        {
            const float4* src = (const float4*)&X[(size_t)(row_base + sr) * 256 + kc * 32 + sh * 16];
            _Float16* dst = &Xs[sr * 40 + sh * 16];
#pragma unroll
            for (int j = 0; j < 4; ++j) {
                float4 v = src[j];
                v4h p = {(_Float16)v.x, (_Float16)v.y, (_Float16)v.z, (_Float16)v.w};
                *(v4h*)&dst[j * 4] = p;
            }
        }
        __syncthreads();

        v8h wf[2][2];
#pragma unroll
        for (int cb = 0; cb < 2; ++cb)
#pragma unroll
            for (int ft = 0; ft < 2; ++ft)
                wf[cb][ft] = *(const v8h*)&Wt[((size_t)cb * 128 + wave * 32 + ft * 16 + l16) * 256 + kc * 32 + quad * 8];

#pragma unroll
        for (int nt = 0; nt < 8; ++nt) {
            v8h xf = *(v8h*)&Xs[(nt * 16 + l16) * 40 + quad * 8];
            acc[0][0][nt] = __builtin_amdgcn_mfma_f32_16x16x32_f16(wf[0][0], xf, acc[0][0][nt], 0, 0, 0);
            acc[0][1][nt] = __builtin_amdgcn_mfma_f32_16x16x32_f16(wf[0][1], xf, acc[0][1][nt], 0, 0, 0);
            acc[1][0][nt] = __builtin_amdgcn_mfma_f32_16x16x32_f16(wf[1][0], xf, acc[1][0][nt], 0, 0, 0);
            acc[1][1][nt] = __builtin_amdgcn_mfma_f32_16x16x32_f16(wf[1][1], xf, acc[1][1][nt], 0, 0, 0);
        }
        __syncthreads();
    }

#pragma unroll
    for (int nt = 0; nt < 8; ++nt) {
        const int R = row_base + nt * 16 + l16;
        const int b = R / N_;
        const int n = R - b * N_;
        const size_t off = ((size_t)(n * 8 + b)) * 128 + wave * 32 + quad * 4;
#pragma unroll
        for (int cb = 0; cb < 2; ++cb) {
            __half* base = (cb ? pd : ps) + off;
#pragma unroll
            for (int ft = 0; ft < 2; ++ft) {
                f32x4 a = acc[cb][ft][nt];
                v4h h = {(_Float16)a.x, (_Float16)a.y, (_Float16)a.z, (_Float16)a.w};
                *(v4h*)(base + ft * 16) = h;
            }
        }
    }
}

// ---------------------------------------------------------------- K2: edge scores, 2 edges/wave -> scS[pos][8]
__global__ __launch_bounds__(256) void k2_scores(const __half* __restrict__ ps,
                                                 const __half* __restrict__ pd,
                                                 const int4* __restrict__ esort,
                                                 const __half* __restrict__ b1h,
                                                 const __half* __restrict__ w2h,
                                                 const float* __restrict__ b2,
                                                 const float* __restrict__ eattr,
                                                 float* __restrict__ scS) {
    const int tid = threadIdx.x;
    const int wave = tid >> 6;
    const int lane = tid & 63;
    const int bid = blockIdx.x;                    // 0..19999
    const int lb = (bid & 7) * 2500 + (bid >> 3);  // XCD swizzle
    const int e0 = lb * 8 + wave * 2;

    const int b = lane >> 3;
    const int hi = (lane & 7) * 16;

    v2h b1p[8], w2p[8];
    {
        const v2h* bp = (const v2h*)(b1h + hi);
        const v2h* wp = (const v2h*)(w2h + hi);
#pragma unroll
        for (int j = 0; j < 8; j++) { b1p[j] = bp[j]; w2p[j] = wp[j]; }
    }
    const float bias2 = b2[0];
    const v2h slp = {(_Float16)SLOPE, (_Float16)SLOPE};

#pragma unroll
    for (int q = 0; q < 2; q++) {
        const int e = e0 + q;
        const int4 er = esort[e];
        const int src = er.x, dst = er.y, orig = er.z;

        const float4* aps = (const float4*)&ps[((size_t)src * 8 + b) * 128 + hi];
        const float4* apd = (const float4*)&pd[((size_t)dst * 8 + b) * 128 + hi];
        float4 rs[2] = {aps[0], aps[1]};
        float4 rd[2] = {apd[0], apd[1]};
        const v2h* sv = (const v2h*)rs;
        const v2h* dv = (const v2h*)rd;

        float acc = 0.f;
#pragma unroll
        for (int j = 0; j < 8; j++) {
            v2h x = sv[j] + dv[j] + b1p[j];
            v2h l = __builtin_elementwise_max(x, x * slp);   // LeakyReLU, slope<1
            acc = dot2f(l, w2p[j], acc);
        }
        acc += __shfl_xor(acc, 1);
        acc += __shfl_xor(acc, 2);
        acc += __shfl_xor(acc, 4);

        if ((lane & 7) == 0) {
            scS[(size_t)e * 8 + b] = (acc + bias2) * eattr[orig];
        }
    }
}

// ---------------------------------------------------------------- K3s: per-chunk per-batch (max, shifted exp-sum)
__global__ __launch_bounds__(256) void k3s_stats(const float* __restrict__ scS,
                                                 float* __restrict__ pmax,
                                                 double* __restrict__ psum) {
    const int tid = threadIdx.x;
    const int wave = tid >> 6, lane = tid & 63;
    const int base = blockIdx.x * SEB_;

    float fm[8];
#pragma unroll
    for (int j = 0; j < 8; j++) fm[j] = -3.4e38f;
    for (int i = tid; i < SEB_; i += 256) {
        const float4* s4 = (const float4*)&scS[(size_t)(base + i) * 8];
        float4 a = s4[0], b = s4[1];
        fm[0] = fmaxf(fm[0], a.x); fm[1] = fmaxf(fm[1], a.y);
        fm[2] = fmaxf(fm[2], a.z); fm[3] = fmaxf(fm[3], a.w);
        fm[4] = fmaxf(fm[4], b.x); fm[5] = fmaxf(fm[5], b.y);
        fm[6] = fmaxf(fm[6], b.z); fm[7] = fmaxf(fm[7], b.w);
    }
#pragma unroll
    for (int k = 1; k <= 32; k <<= 1)
#pragma unroll
        for (int j = 0; j < 8; j++) fm[j] = fmaxf(fm[j], __shfl_xor(fm[j], k));
    __shared__ float lmax[4][8];
    if (lane == 0)
#pragma unroll
        for (int j = 0; j < 8; j++) lmax[wave][j] = fm[j];
    __syncthreads();
    float m[8];
#pragma unroll
    for (int j = 0; j < 8; j++)
        m[j] = fmaxf(fmaxf(lmax[0][j], lmax[1][j]), fmaxf(lmax[2][j], lmax[3][j]));

    double s[8];
#pragma unroll
    for (int j = 0; j < 8; j++) s[j] = 0.0;
    for (int i = tid; i < SEB_; i += 256) {
        const float4* s4 = (const float4*)&scS[(size_t)(base + i) * 8];
        float4 a = s4[0], b = s4[1];
        s[0] += (double)expf(a.x - m[0]); s[1] += (double)expf(a.y - m[1]);
        s[2] += (double)expf(a.z - m[2]); s[3] += (double)expf(a.w - m[3]);
        s[4] += (double)expf(b.x - m[4]); s[5] += (double)expf(b.y - m[5]);
        s[6] += (double)expf(b.z - m[6]); s[7] += (double)expf(b.w - m[7]);
    }
#pragma unroll
    for (int k = 1; k <= 32; k <<= 1)
#pragma unroll
        for (int j = 0; j < 8; j++) s[j] += __shfl_xor(s[j], k);
    __shared__ double lsum[4][8];
    if (lane == 0)
#pragma unroll
        for (int j = 0; j < 8; j++) lsum[wave][j] = s[j];
    __syncthreads();
    if (tid < 8) {
        pmax[blockIdx.x * 8 + tid] = m[tid];
        psum[blockIdx.x * 8 + tid] = lsum[0][tid] + lsum[1][tid] + lsum[2][tid] + lsum[3][tid];
    }
}

// stats prologue: reduce 64 chunk (m_c,l_c) -> shared m[8], inv[8]. Call from wave 0.
static __device__ __forceinline__ void stats_combine(const float* __restrict__ pmax,
                                                     const double* __restrict__ psum,
                                                     int tid, float* smx, float* sinvx) {
    if (tid < 64) {
        float v[8];
        const float4* p4 = (const float4*)&pmax[tid * 8];
        float4 a = p4[0], b = p4[1];
        v[0] = a.x; v[1] = a.y; v[2] = a.z; v[3] = a.w;
        v[4] = b.x; v[5] = b.y; v[6] = b.z; v[7] = b.w;
        float mc[8];
#pragma unroll
        for (int j = 0; j < 8; j++) mc[j] = v[j];
#pragma unroll
        for (int k = 1; k <= 32; k <<= 1)
#pragma unroll
            for (int j = 0; j < 8; j++) v[j] = fmaxf(v[j], __shfl_xor(v[j], k));
        // v = global max (all lanes). Z = sum l_c * exp(m_c - m)
        double z[8];
#pragma unroll
        for (int j = 0; j < 8; j++)
            z[j] = psum[tid * 8 + j] * (double)expf(mc[j] - v[j]);
#pragma unroll
        for (int k = 1; k <= 32; k <<= 1)
#pragma unroll
            for (int j = 0; j < 8; j++) z[j] += __shfl_xor(z[j], k);
        if (tid == 0)
#pragma unroll
            for (int j = 0; j < 8; j++) { smx[j] = v[j]; sinvx[j] = (float)(1.0 / z[j]); }
    }
}

// ---------------------------------------------------------------- K3e: normalize -> wout (coalesced)
__global__ __launch_bounds__(256) void k3e_norm(const float* __restrict__ scS,
                                                const int* __restrict__ rank,
                                                const float* __restrict__ pmax,
                                                const double* __restrict__ psum,
                                                float* __restrict__ wout) {
    const int tid = threadIdx.x;
    __shared__ float smx[8], sinvx[8];
    stats_combine(pmax, psum, tid, smx, sinvx);
    __syncthreads();

    const int e = blockIdx.x * 256 + tid;
    const int p = rank[e];
    const float4* s4 = (const float4*)&scS[(size_t)p * 8];
    float4 a = s4[0], b = s4[1];
    float wv[8];
    wv[0] = expf(a.x - smx[0]) * sinvx[0]; wv[1] = expf(a.y - smx[1]) * sinvx[1];
    wv[2] = expf(a.z - smx[2]) * sinvx[2]; wv[3] = expf(a.w - smx[3]) * sinvx[3];
    wv[4] = expf(b.x - smx[4]) * sinvx[4]; wv[5] = expf(b.y - smx[5]) * sinvx[5];
    wv[6] = expf(b.z - smx[6]) * sinvx[6]; wv[7] = expf(b.w - smx[7]) * sinvx[7];
#pragma unroll
    for (int j = 0; j < 8; j++) wout[(size_t)j * E_ + e] = wv[j];   // coalesced
}

// ---------------------------------------------------------------- K3f: bucket-aligned node-weight binning
// grid (16 buckets, 8 subs). Edges of bucket are contiguous in sorted arrays.
__global__ __launch_bounds__(256) void k3f_bin(const int4* __restrict__ esort,
                                               const float* __restrict__ scS,
                                               const unsigned char* __restrict__ cmT,
                                               const float* __restrict__ pmax,
                                               const double* __restrict__ psum,
                                               const int* __restrict__ bstart,
                                               float* __restrict__ Wpf,
                                               float* __restrict__ Wpm) {
    const int bucket = blockIdx.x;  // 0..15
    const int sub = blockIdx.y;     // 0..7
    const int tid = threadIdx.x;

    __shared__ float smx[8], sinvx[8];
    stats_combine(pmax, psum, tid, smx, sinvx);

    __shared__ float lWf[NPB_ * 8];   // 20 KB
    __shared__ float lWm[NPB_ * 8];   // 20 KB
    for (int i = tid; i < NPB_ * 8; i += 256) { lWf[i] = 0.f; lWm[i] = 0.f; }
    __syncthreads();

    float m[8], inv[8];
#pragma unroll
    for (int j = 0; j < 8; j++) { m[j] = smx[j]; inv[j] = sinvx[j]; }

    const int bs = bstart[bucket], be = bstart[bucket + 1];
    const int len = be - bs;
    const int s0 = bs + (int)((long long)len * sub / 8);
    const int s1 = bs + (int)((long long)len * (sub + 1) / 8);
    const int nbase = bucket * NPB_;

    for (int p = s0 + tid; p < s1; p += 256) {
        const int4 er = esort[p];
        const int src = er.x;
        const int rel = er.y - nbase;
        const float4* s4 = (const float4*)&scS[(size_t)p * 8];
        float4 a = s4[0], b = s4[1];
        float wv[8];
        wv[0] = expf(a.x - m[0]) * inv[0]; wv[1] = expf(a.y - m[1]) * inv[1];
        wv[2] = expf(a.z - m[2]) * inv[2]; wv[3] = expf(a.w - m[3]) * inv[3];
        wv[4] = expf(b.x - m[4]) * inv[4]; wv[5] = expf(b.y - m[5]) * inv[5];
        wv[6] = expf(b.z - m[6]) * inv[6]; wv[7] = expf(b.w - m[7]) * inv[7];
        const unsigned long long mm = *(const unsigned long long*)&cmT[src * 8];
        float* lf = &lWf[rel * 8];
        float* lm = &lWm[rel * 8];
#pragma unroll
        for (int j = 0; j < 8; j++) {
            atomicAdd(&lf[j], wv[j]);
            if ((mm >> (8 * j)) & 1ull) atomicAdd(&lm[j], wv[j]);
        }
    }
    __syncthreads();

    float* of = Wpf + ((size_t)bucket * 8 + sub) * (NPB_ * 8);
    float* om = Wpm + ((size_t)bucket * 8 + sub) * (NPB_ * 8);
    for (int i = tid; i < NPB_ * 8; i += 256) { of[i] = lWf[i]; om[i] = lWm[i]; }
}

// ---------------------------------------------------------------- K3g: reduce 8 sub-partials -> WfT/WmT [n][8]
__global__ __launch_bounds__(256) void k3g_reduce(const float* __restrict__ Wpf,
                                                  const float* __restrict__ Wpm,
                                                  float* __restrict__ WfT,
                                                  float* __restrict__ WmT) {
    const int i = blockIdx.x * 256 + threadIdx.x;  // < N_*8
    if (i >= N_ * 8) return;
    const int n = i >> 3, b = i & 7;
    const int bucket = n / NPB_;
    const int rel = n - bucket * NPB_;
    float sf = 0.f, sm = 0.f;
#pragma unroll
    for (int sub = 0; sub < 8; sub++) {
        const size_t off = ((size_t)bucket * 8 + sub) * (NPB_ * 8) + rel * 8 + b;
        sf += Wpf[off];
        sm += Wpm[off];
    }
    WfT[i] = sf;
    WmT[i] = sm;
}

// ---------------------------------------------------------------- K4b: dense weighted sum over X
__global__ __launch_bounds__(256) void k4b_wsum(const float* __restrict__ X,
                                                const float* __restrict__ WmT,
                                                const float* __restrict__ WfT,
                                                float* __restrict__ gpart) {
    const int c = blockIdx.x;
    const int b = blockIdx.y;
    const int tx = threadIdx.x & 63;
    const int ty = threadIdx.x >> 6;
    const int npc = N_ / NCHUNK;
    const int n0 = c * npc;

    const float4* X4 = (const float4*)(X + (size_t)b * N_ * 256);
    float4 am = {0.f, 0.f, 0.f, 0.f};
    float4 af = {0.f, 0.f, 0.f, 0.f};

    for (int n = n0 + ty; n < n0 + npc; n += 4) {
        float wm = WmT[n * 8 + b];
        float wf = WfT[n * 8 + b];
        float4 v = X4[(size_t)n * 64 + tx];
        am.x = fmaf(wm, v.x, am.x); am.y = fmaf(wm, v.y, am.y);
        am.z = fmaf(wm, v.z, am.z); am.w = fmaf(wm, v.w, am.w);
        af.x = fmaf(wf, v.x, af.x); af.y = fmaf(wf, v.y, af.y);
        af.z = fmaf(wf, v.z, af.z); af.w = fmaf(wf, v.w, af.w);
    }

    __shared__ float4 red[256];
    red[threadIdx.x] = am;
    __syncthreads();
    if (ty == 0) {
        float4 r1 = red[tx + 64], r2 = red[tx + 128], r3 = red[tx + 192];
        am.x += r1.x + r2.x + r3.x; am.y += r1.y + r2.y + r3.y;
        am.z += r1.z + r2.z + r3.z; am.w += r1.w + r2.w + r3.w;
    }
    __syncthreads();
    red[threadIdx.x] = af;
    __syncthreads();
    if (ty == 0) {
        float4 r1 = red[tx + 64], r2 = red[tx + 128], r3 = red[tx + 192];
        af.x += r1.x + r2.x + r3.x; af.y += r1.y + r2.y + r3.y;
        af.z += r1.z + r2.z + r3.z; af.w += r1.w + r2.w + r3.w;
        float4* gp4 = (float4*)gpart;
        gp4[((c * 2 + 0) * 8 + b) * 64 + tx] = am;
        gp4[((c * 2 + 1) * 8 + b) * 64 + tx] = af;
    }
}

// ---------------------------------------------------------------- K5: finalize
__global__ __launch_bounds__(256) void k5_final(const float* __restrict__ gpart,
                                                const float* __restrict__ cnt,
                                                float* __restrict__ gf) {
    const int b = blockIdx.x;
    const int d = threadIdx.x;
    float sm = 0.f, sf = 0.f;
    for (int c = 0; c < NCHUNK; c++) {
        sm += gpart[((c * 2 + 0) * 8 + b) * 256 + d];
        sf += gpart[((c * 2 + 1) * 8 + b) * 256 + d];
    }
    const float cn = cnt[b];
    gf[b * 256 + d] = (cn > 0.f) ? (sm / cn) : (sf / (float)N_);
}

// ---------------------------------------------------------------- launch
static inline char* align16(char* p) {
    return (char*)(((uintptr_t)p + 15) & ~(uintptr_t)15);
}

extern "C" void kernel_launch(void* const* d_in, const int* in_sizes, int n_in,
                              void* d_out, int out_size, void* d_ws, size_t ws_size,
                              hipStream_t stream) {
    const float* X     = (const float*)d_in[0];
    const float* eattr = (const float*)d_in[1];
    const float* W1    = (const float*)d_in[2];
    const float* b1    = (const float*)d_in[3];
    const float* W2    = (const float*)d_in[4];
    const float* b2    = (const float*)d_in[5];
    const int*   eidx_raw = (const int*)d_in[6];
    const unsigned char* mask8 = (const unsigned char*)d_in[7];
    const unsigned int*  mask32 = (const unsigned int*)d_in[7];

    float* out  = (float*)d_out;
    float* gf   = out;          // [B,D]
    float* wout = out + 2048;   // [B,E]

    // persistent region
    char* cur = (char*)d_ws;
    __half* ps_h = (__half*)cur;             cur += (size_t)N_ * 8 * 128 * 2;   // 20.48 MB
    __half* pd_h = (__half*)cur;             cur += (size_t)N_ * 8 * 128 * 2;
    __half* Wt   = (__half*)cur;             cur += 2 * 128 * 256 * 2;
    int* ce      = (int*)cur;                cur += 2 * E_ * 4;
    unsigned char* cmT = (unsigned char*)cur; cur += N_ * 8;
    unsigned char* cm  = (unsigned char*)cur; cur += B_ * N_;
    cur = align16(cur);
    float* cnt   = (float*)cur;              cur += 8 * 4;
    int* flags   = (int*)cur;                cur += 2 * 4;
    cur = align16(cur);
    float* pmax  = (float*)cur;              cur += SB_ * 8 * 4;
    cur = align16(cur);
    double* psum = (double*)cur;             cur += SB_ * 8 * 8;
    float* gpart = (float*)cur;              cur += NCHUNK * 2 * 8 * 256 * 4;
    int* hpart   = (int*)cur;                cur += NB_ * BINS_ * 4;
    int* offsetG = (int*)cur;                cur += NB_ * BINS_ * 4;
    int* bstart  = (int*)cur;                cur += 32 * 4;
    cur = align16(cur);
    int4* esort  = (int4*)cur;               cur += (size_t)E_ * 16;
    int* rankB   = (int*)cur;                cur += E_ * 4;
    __half* b1h  = (__half*)cur;             cur += 128 * 2;
    __half* w2h  = (__half*)cur;             cur += 128 * 2;
    cur = align16(cur);
    float* scS   = (float*)cur;              cur += (size_t)E_ * 8 * 4;

    // overlay region (reuses ps_h: dead after k2/k3s/k3e... used only by k3f/k3g)
    char* ocur = (char*)d_ws;
    float* Wpf = (float*)ocur;               ocur += (size_t)16 * 8 * NPB_ * 8 * 4;  // 2.56 MB
    float* Wpm = (float*)ocur;               ocur += (size_t)16 * 8 * NPB_ * 8 * 4;
    float* WfT = (float*)ocur;               ocur += N_ * 8 * 4;
    float* WmT = (float*)ocur;               ocur += N_ * 8 * 4;

    hipLaunchKernelGGL(k_detect, dim3(1), dim3(64), 0, stream, eidx_raw, mask32, flags);
    hipLaunchKernelGGL(k_canon, dim3(1250), dim3(256), 0, stream,
                       eidx_raw, mask8, mask32, flags, W1, b1, W2,
                       ce, cm, cmT, Wt, b1h, w2h);
    hipLaunchKernelGGL(khist, dim3(NB_ + 8), dim3(256), 0, stream, ce, cm, hpart, cnt);
    hipLaunchKernelGGL(kprefix, dim3(1), dim3(256), 0, stream, hpart, offsetG, bstart);
    hipLaunchKernelGGL(kscatter, dim3(NB_), dim3(256), 0, stream, ce, offsetG, esort, rankB);
    hipLaunchKernelGGL(k1_mfma, dim3(625), dim3(256), 0, stream, X, Wt, ps_h, pd_h);
    hipLaunchKernelGGL(k2_scores, dim3(E_ / 8), dim3(256), 0, stream,
                       ps_h, pd_h, esort, b1h, w2h, b2, eattr, scS);
    hipLaunchKernelGGL(k3s_stats, dim3(SB_), dim3(256), 0, stream, scS, pmax, psum);
    hipLaunchKernelGGL(k3e_norm, dim3(E_ / 256), dim3(256), 0, stream,
                       scS, rankB, pmax, psum, wout);
    hipLaunchKernelGGL(k3f_bin, dim3(16, 8), dim3(256), 0, stream,
                       esort, scS, cmT, pmax, psum, bstart, Wpf, Wpm);
    hipLaunchKernelGGL(k3g_reduce, dim3((N_ * 8 + 255) / 256), dim3(256), 0, stream,
                       Wpf, Wpm, WfT, WmT);
    hipLaunchKernelGGL(k4b_wsum, dim3(NCHUNK, 8), dim3(256), 0, stream, X, WmT, WfT, gpart);
    hipLaunchKernelGGL(k5_final, dim3(8), dim3(256), 0, stream, gpart, cnt, gf);
}